// Round 11
// baseline (609.843 us; speedup 1.0000x reference)
//
#include <hip/hip_runtime.h>

typedef __bf16 bf16x8 __attribute__((ext_vector_type(8)));
typedef __bf16 bf16x4 __attribute__((ext_vector_type(4)));
typedef float  f32x4  __attribute__((ext_vector_type(4)));

#define MFMA16(a, b, c) __builtin_amdgcn_mfma_f32_16x16x32_bf16((a), (b), (c), 0, 0, 0)

__device__ __forceinline__ float sigm(float x) { return 1.0f / (1.0f + __expf(-x)); }

// ---- packed bf16 weight layout (element offsets inside d_ws) ----
enum : int {
  ENC_W0_OFF  = 0,        // 16 x 128 x 256
  ENC_W1_OFF  = 524288,   // 16 x 64 x 128
  ENC_W2_OFF  = 655360,   // 16 x 32 x 64
  DEC_W0_OFF  = 688128,   // 16 x 64 x 32
  DEC_W1_OFF  = 720896,   // 16 x 128 x 64
  DEC_W2_OFF  = 851968,   // 16 x 256 x 128
  COMP_W0_OFF = 1376256,  // 256 x 512  (folded [z,z])
  COMP_W1_OFF = 1507328,  // 128 x 768
  COMP_W2_OFF = 1605632,  // 64 x 640
  COMP_W3_OFF = 1646592,  // 32 x 576
  COMP_W4_OFF = 1665024,  // 16 x 544
  COMP_W5_OFF = 1673728,  // 32 x 544  (528 padded to 544, pad = 0)
  DCMP_W0_OFF = 1691136,  // 256 x 32  (folded)
  DCMP_W1_OFF = 1699328,  // 128 x 288
  DCMP_W2_OFF = 1736192,  // 64 x 160
  DCMP_W3_OFF = 1746432,  // 32 x 96
  DCMP_W4_OFF = 1749504,  // 16 x 64
  DCMP_W5_OFF = 1750528,  // 512 x 64  (48 padded to 64, pad = 0)
  W_TOTAL     = 1783296,
};

#define ZS_BYTES_OFF (4u * 1024u * 1024u)  // z_stack, overwritten in-place by z_stack_hat

// =============================== weight prep ===============================
__global__ void prep_kernel(
    const float* __restrict__ ew0, const float* __restrict__ ew1, const float* __restrict__ ew2,
    const float* __restrict__ dw0, const float* __restrict__ dw1, const float* __restrict__ dw2,
    const float* __restrict__ cw0, const float* __restrict__ cw1, const float* __restrict__ cw2,
    const float* __restrict__ cw3, const float* __restrict__ cw4, const float* __restrict__ cw5,
    const float* __restrict__ xw0, const float* __restrict__ xw1, const float* __restrict__ xw2,
    const float* __restrict__ xw3, const float* __restrict__ xw4, const float* __restrict__ xw5,
    __bf16* __restrict__ wb)
{
  for (int i = blockIdx.x * blockDim.x + threadIdx.x; i < W_TOTAL; i += gridDim.x * blockDim.x) {
    float v;
    if      (i < ENC_W1_OFF)  v = ew0[i - ENC_W0_OFF];
    else if (i < ENC_W2_OFF)  v = ew1[i - ENC_W1_OFF];
    else if (i < DEC_W0_OFF)  v = ew2[i - ENC_W2_OFF];
    else if (i < DEC_W1_OFF)  v = dw0[i - DEC_W0_OFF];
    else if (i < DEC_W2_OFF)  v = dw1[i - DEC_W1_OFF];
    else if (i < COMP_W0_OFF) v = dw2[i - DEC_W2_OFF];
    else if (i < COMP_W1_OFF) { int t = i - COMP_W0_OFF; int o = t >> 9, c = t & 511;
                                v = cw0[o * 1024 + c] + cw0[o * 1024 + 512 + c]; }
    else if (i < COMP_W2_OFF) v = cw1[i - COMP_W1_OFF];
    else if (i < COMP_W3_OFF) v = cw2[i - COMP_W2_OFF];
    else if (i < COMP_W4_OFF) v = cw3[i - COMP_W3_OFF];
    else if (i < COMP_W5_OFF) v = cw4[i - COMP_W4_OFF];
    else if (i < DCMP_W0_OFF) { int t = i - COMP_W5_OFF; int o = t / 544, c = t % 544;
                                v = (c < 528) ? cw5[o * 528 + c] : 0.0f; }
    else if (i < DCMP_W1_OFF) { int t = i - DCMP_W0_OFF; int o = t >> 5, c = t & 31;
                                v = xw0[o * 64 + c] + xw0[o * 64 + 32 + c]; }
    else if (i < DCMP_W2_OFF) v = xw1[i - DCMP_W1_OFF];
    else if (i < DCMP_W3_OFF) v = xw2[i - DCMP_W2_OFF];
    else if (i < DCMP_W4_OFF) v = xw3[i - DCMP_W3_OFF];
    else if (i < DCMP_W5_OFF) v = xw4[i - DCMP_W4_OFF];
    else                      { int t = i - DCMP_W5_OFF; int o = t >> 6, c = t & 63;
                                v = (c < 48) ? xw5[o * 48 + c] : 0.0f; }
    wb[i] = (__bf16)v;
  }
}

// =============================== encoder ===================================
// Single change vs R7/R10: L0 reads x fragments DIRECTLY from global (fp32,
// 2x float4 per fragment; 4-lane groups cover 128 contiguous bytes). No xs
// staging, no staging barrier. LDS = h1+h2 only (26.6 KB) -> 4 blocks/CU.
// L2 absorbs the 4x intra-block re-read; HBM traffic unchanged.
__global__ __launch_bounds__(256, 4)
void enc_kernel(const float* __restrict__ x, const __bf16* __restrict__ wb,
                const float* __restrict__ b0, const float* __restrict__ b1,
                const float* __restrict__ b2, __bf16* __restrict__ zout)
{
  __shared__ __bf16 h1[64 * 136];
  __shared__ __bf16 h2[64 * 72];
  const int e = blockIdx.y;
  const int m0 = blockIdx.x * 64;
  const int tid = threadIdx.x;
  const int lane = tid & 63, wv = tid >> 6;
  const int l15 = lane & 15, hi8 = (lane >> 4) * 8, rloc = (lane >> 4) * 4;

  // L0: N=128, K=256. wave covers cols [wv*32, wv*32+32); x straight from HBM.
  {
    const __bf16* W = wb + ENC_W0_OFF + e * 32768;
    const float* xb = x + (size_t)m0 * 4096 + e * 256 + hi8;
    f32x4 acc[4][2];
    #pragma unroll
    for (int cf = 0; cf < 2; ++cf) {
      float bv = b0[e * 128 + wv * 32 + cf * 16 + l15];
      f32x4 bvv = {bv, bv, bv, bv};
      #pragma unroll
      for (int rf = 0; rf < 4; ++rf) acc[rf][cf] = bvv;
    }
    #pragma unroll
    for (int ks = 0; ks < 8; ++ks) {
      bf16x8 bb[2];
      #pragma unroll
      for (int cf = 0; cf < 2; ++cf)
        bb[cf] = *(const bf16x8*)(W + (size_t)(wv * 32 + cf * 16 + l15) * 256 + ks * 32 + hi8);
      #pragma unroll
      for (int rf = 0; rf < 4; ++rf) {
        const float* p = xb + (size_t)(rf * 16 + l15) * 4096 + ks * 32;
        float4 u0 = *(const float4*)p;
        float4 u1 = *(const float4*)(p + 4);
        bf16x8 a = {(__bf16)u0.x, (__bf16)u0.y, (__bf16)u0.z, (__bf16)u0.w,
                    (__bf16)u1.x, (__bf16)u1.y, (__bf16)u1.z, (__bf16)u1.w};
        #pragma unroll
        for (int cf = 0; cf < 2; ++cf)
          acc[rf][cf] = MFMA16(a, bb[cf], acc[rf][cf]);
      }
    }
    #pragma unroll
    for (int rf = 0; rf < 4; ++rf)
      #pragma unroll
      for (int cf = 0; cf < 2; ++cf)
        #pragma unroll
        for (int r = 0; r < 4; ++r)
          h1[(rf * 16 + rloc + r) * 136 + wv * 32 + cf * 16 + l15] = (__bf16)sigm(acc[rf][cf][r]);
  }
  __syncthreads();

  // L1: N=64, K=128
  {
    const __bf16* W = wb + ENC_W1_OFF + e * 8192;
    f32x4 acc[4];
    float bv = b1[e * 64 + wv * 16 + l15];
    f32x4 bvv = {bv, bv, bv, bv};
    #pragma unroll
    for (int rf = 0; rf < 4; ++rf) acc[rf] = bvv;
    #pragma unroll
    for (int ks = 0; ks < 4; ++ks) {
      bf16x8 a[4];
      #pragma unroll
      for (int rf = 0; rf < 4; ++rf) a[rf] = *(const bf16x8*)&h1[(rf * 16 + l15) * 136 + ks * 32 + hi8];
      bf16x8 bb = *(const bf16x8*)(W + (size_t)(wv * 16 + l15) * 128 + ks * 32 + hi8);
      #pragma unroll
      for (int rf = 0; rf < 4; ++rf) acc[rf] = MFMA16(a[rf], bb, acc[rf]);
    }
    #pragma unroll
    for (int rf = 0; rf < 4; ++rf)
      #pragma unroll
      for (int r = 0; r < 4; ++r)
        h2[(rf * 16 + rloc + r) * 72 + wv * 16 + l15] = (__bf16)sigm(acc[rf][r]);
  }
  __syncthreads();

  // L2: N=32, K=64, no sigmoid. waves 0,1 only.
  if (wv < 2) {
    const __bf16* W = wb + ENC_W2_OFF + e * 2048;
    f32x4 acc[4];
    float bv = b2[e * 32 + wv * 16 + l15];
    f32x4 bvv = {bv, bv, bv, bv};
    #pragma unroll
    for (int rf = 0; rf < 4; ++rf) acc[rf] = bvv;
    #pragma unroll
    for (int ks = 0; ks < 2; ++ks) {
      bf16x8 a[4];
      #pragma unroll
      for (int rf = 0; rf < 4; ++rf) a[rf] = *(const bf16x8*)&h2[(rf * 16 + l15) * 72 + ks * 32 + hi8];
      bf16x8 bb = *(const bf16x8*)(W + (size_t)(wv * 16 + l15) * 64 + ks * 32 + hi8);
      #pragma unroll
      for (int rf = 0; rf < 4; ++rf) acc[rf] = MFMA16(a[rf], bb, acc[rf]);
    }
    #pragma unroll
    for (int rf = 0; rf < 4; ++rf)
      #pragma unroll
      for (int r = 0; r < 4; ++r)
        zout[(size_t)(m0 + rf * 16 + rloc + r) * 512 + e * 32 + wv * 16 + l15] = (__bf16)acc[rf][r];
  }
}

// ==================== 8-wave residual layer, 64-row tile ===================
template<int NF, int KT, int ZKS, int ZLD, int SKS, int SLD, int DLD, bool SIG>
__device__ __forceinline__ void rlayer(const __bf16* __restrict__ W, const float* __restrict__ bias,
                                       const __bf16* __restrict__ zp, const __bf16* __restrict__ sp,
                                       __bf16* __restrict__ dst,
                                       int wv, int l15, int hi8, int rloc)
{
  constexpr int NJ = (NF >= 32) ? 4 : ((NF >= 16) ? 2 : 1);
  constexpr int NR = (NF >= 8) ? 4 : ((NF == 4) ? 2 : 1);
  int c0, row0;
  if constexpr (NF >= 8)       { c0 = wv;      row0 = 0; }
  else if constexpr (NF == 4)  { c0 = wv & 3;  row0 = (wv >> 2) * 32; }
  else if constexpr (NF == 2)  { c0 = wv & 1;  row0 = (wv >> 1) * 16; }
  else                         { if (wv >= 4) return; c0 = 0; row0 = wv * 16; }
  f32x4 acc[NR][NJ];
  #pragma unroll
  for (int j = 0; j < NJ; ++j) {
    float bv = bias[(c0 + 8 * j) * 16 + l15];
    f32x4 b4 = {bv, bv, bv, bv};
    #pragma unroll
    for (int rf = 0; rf < NR; ++rf) acc[rf][j] = b4;
  }
  #pragma unroll
  for (int ks = 0; ks < ZKS; ++ks) {
    bf16x8 a[NR];
    #pragma unroll
    for (int rf = 0; rf < NR; ++rf)
      a[rf] = *(const bf16x8*)&zp[(size_t)(row0 + rf * 16 + l15) * ZLD + ks * 32 + hi8];
    #pragma unroll
    for (int j = 0; j < NJ; ++j) {
      bf16x8 b = *(const bf16x8*)&W[(size_t)((c0 + 8 * j) * 16 + l15) * KT + ks * 32 + hi8];
      #pragma unroll
      for (int rf = 0; rf < NR; ++rf) acc[rf][j] = MFMA16(a[rf], b, acc[rf][j]);
    }
  }
  if constexpr (SKS > 0) {
    #pragma unroll
    for (int ks = 0; ks < SKS; ++ks) {
      bf16x8 a[NR];
      #pragma unroll
      for (int rf = 0; rf < NR; ++rf)
        a[rf] = *(const bf16x8*)&sp[(size_t)(row0 + rf * 16 + l15) * SLD + ks * 32 + hi8];
      #pragma unroll
      for (int j = 0; j < NJ; ++j) {
        bf16x8 b = *(const bf16x8*)&W[(size_t)((c0 + 8 * j) * 16 + l15) * KT + ZKS * 32 + ks * 32 + hi8];
        #pragma unroll
        for (int rf = 0; rf < NR; ++rf) acc[rf][j] = MFMA16(a[rf], b, acc[rf][j]);
      }
    }
  }
  #pragma unroll
  for (int j = 0; j < NJ; ++j)
    #pragma unroll
    for (int rf = 0; rf < NR; ++rf)
      #pragma unroll
      for (int r = 0; r < 4; ++r) {
        float v = acc[rf][j][r];
        dst[(size_t)(row0 + rf * 16 + rloc + r) * DLD + (c0 + 8 * j) * 16 + l15] =
            (__bf16)(SIG ? sigm(v) : v);
      }
}

// ===================== middle: comp + decomp fused (R10 verbatim) ==========
struct MidBias {
  const float *c0, *c1, *c2, *c3, *c4, *c5;
  const float *x0, *x1, *x2, *x3, *x4, *x5;
};

__global__ __launch_bounds__(512, 2)
void mid_kernel(const __bf16* __restrict__ zin, const __bf16* __restrict__ wb,
                MidBias mb, __bf16* __restrict__ zhout)
{
  __shared__ __bf16 zs[64 * 520];
  __shared__ __bf16 sA[64 * 264];
  __shared__ __bf16 sB[64 * 136];
  __shared__ __bf16 zsm[64 * 40];
  const int tid = threadIdx.x;
  const int wv = tid >> 6, lane = tid & 63;
  const int l15 = lane & 15, hi8 = (lane >> 4) * 8, rloc = (lane >> 4) * 4;
  const int m0 = blockIdx.x * 64;

  #pragma unroll
  for (int i = 0; i < 8; ++i) {
    int idx = tid + i * 512;
    int r = idx >> 6, c8 = (idx & 63) * 8;
    *(bf16x8*)&zs[r * 520 + c8] = *(const bf16x8*)(zin + (size_t)(m0 + r) * 512 + c8);
  }
  __syncthreads();
  // ---- compressor ----
  rlayer<16, 512, 16, 520, 0,   0, 264, true >(wb + COMP_W0_OFF, mb.c0, zs, nullptr, sA, wv, l15, hi8, rloc); __syncthreads();
  rlayer< 8, 768, 16, 520, 8, 264, 136, true >(wb + COMP_W1_OFF, mb.c1, zs, sA, sB, wv, l15, hi8, rloc); __syncthreads();
  rlayer< 4, 640, 16, 520, 4, 136, 264, true >(wb + COMP_W2_OFF, mb.c2, zs, sB, sA, wv, l15, hi8, rloc); __syncthreads();
  rlayer< 2, 576, 16, 520, 2, 264, 136, true >(wb + COMP_W3_OFF, mb.c3, zs, sA, sB, wv, l15, hi8, rloc); __syncthreads();
  rlayer< 1, 544, 16, 520, 1, 136, 264, true >(wb + COMP_W4_OFF, mb.c4, zs, sB, sA, wv, l15, hi8, rloc);
  for (int i = tid; i < 64 * 16; i += 512) sA[(i >> 4) * 264 + 16 + (i & 15)] = (__bf16)0.0f;
  __syncthreads();
  rlayer< 2, 544, 16, 520, 1, 264, 40, false>(wb + COMP_W5_OFF, mb.c5, zs, sA, zsm, wv, l15, hi8, rloc);
  __syncthreads();
  // ---- decompressor ----
  rlayer<16,  32, 1, 40, 0,   0, 264, true >(wb + DCMP_W0_OFF, mb.x0, zsm, nullptr, sA, wv, l15, hi8, rloc); __syncthreads();
  rlayer< 8, 288, 1, 40, 8, 264, 136, true >(wb + DCMP_W1_OFF, mb.x1, zsm, sA, sB, wv, l15, hi8, rloc); __syncthreads();
  rlayer< 4, 160, 1, 40, 4, 136, 264, true >(wb + DCMP_W2_OFF, mb.x2, zsm, sB, sA, wv, l15, hi8, rloc); __syncthreads();
  rlayer< 2,  96, 1, 40, 2, 264, 136, true >(wb + DCMP_W3_OFF, mb.x3, zsm, sA, sB, wv, l15, hi8, rloc); __syncthreads();
  rlayer< 1,  64, 1, 40, 1, 136, 264, true >(wb + DCMP_W4_OFF, mb.x4, zsm, sB, sA, wv, l15, hi8, rloc);
  for (int i = tid; i < 64 * 16; i += 512) sA[(i >> 4) * 264 + 16 + (i & 15)] = (__bf16)0.0f;
  __syncthreads();
  rlayer<32,  64, 1, 40, 1, 264, 512, false>(wb + DCMP_W5_OFF, mb.x5, zsm, sA,
                                             zhout + (size_t)m0 * 512, wv, l15, hi8, rloc);
}

// =============================== decoder (R7 verbatim) =====================
__global__ __launch_bounds__(256, 4)
void dec_kernel(const __bf16* __restrict__ zin, const __bf16* __restrict__ wb,
                const float* __restrict__ b0, const float* __restrict__ b1,
                const float* __restrict__ b2, float* __restrict__ out)
{
  __shared__ __bf16 zs[64][40];
  __shared__ __bf16 h1[64][72];
  __shared__ __bf16 h2[64][136];
  const int e = blockIdx.y;
  const int m0 = blockIdx.x * 64;
  const int tid = threadIdx.x;
  const int lane = tid & 63, wv = tid >> 6;
  const int l15 = lane & 15, hi8 = (lane >> 4) * 8, rloc = (lane >> 4) * 4;

  {
    int r = tid >> 2, c = (tid & 3) * 8;
    *(bf16x8*)&zs[r][c] = *(const bf16x8*)(zin + (size_t)(m0 + r) * 512 + e * 32 + c);
  }
  __syncthreads();

  // L0: N=64, K=32
  {
    const __bf16* W = wb + DEC_W0_OFF + e * 2048;
    f32x4 acc[4];
    float bv = b0[e * 64 + wv * 16 + l15];
    f32x4 bvv = {bv, bv, bv, bv};
    #pragma unroll
    for (int rf = 0; rf < 4; ++rf) acc[rf] = bvv;
    bf16x8 a[4];
    #pragma unroll
    for (int rf = 0; rf < 4; ++rf) a[rf] = *(const bf16x8*)&zs[rf * 16 + l15][hi8];
    bf16x8 bb = *(const bf16x8*)(W + (size_t)(wv * 16 + l15) * 32 + hi8);
    #pragma unroll
    for (int rf = 0; rf < 4; ++rf) acc[rf] = MFMA16(a[rf], bb, acc[rf]);
    #pragma unroll
    for (int rf = 0; rf < 4; ++rf)
      #pragma unroll
      for (int r = 0; r < 4; ++r)
        h1[rf * 16 + rloc + r][wv * 16 + l15] = (__bf16)sigm(acc[rf][r]);
  }
  __syncthreads();

  // L1: N=128, K=64
  {
    const __bf16* W = wb + DEC_W1_OFF + e * 8192;
    f32x4 acc[4][2];
    #pragma unroll
    for (int cf = 0; cf < 2; ++cf) {
      float bv = b1[e * 128 + wv * 32 + cf * 16 + l15];
      f32x4 bvv = {bv, bv, bv, bv};
      #pragma unroll
      for (int rf = 0; rf < 4; ++rf) acc[rf][cf] = bvv;
    }
    #pragma unroll
    for (int ks = 0; ks < 2; ++ks) {
      bf16x8 a[4], bb[2];
      #pragma unroll
      for (int rf = 0; rf < 4; ++rf) a[rf] = *(const bf16x8*)&h1[rf * 16 + l15][ks * 32 + hi8];
      #pragma unroll
      for (int cf = 0; cf < 2; ++cf)
        bb[cf] = *(const bf16x8*)(W + (size_t)(wv * 32 + cf * 16 + l15) * 64 + ks * 32 + hi8);
      #pragma unroll
      for (int rf = 0; rf < 4; ++rf)
        #pragma unroll
        for (int cf = 0; cf < 2; ++cf)
          acc[rf][cf] = MFMA16(a[rf], bb[cf], acc[rf][cf]);
    }
    #pragma unroll
    for (int rf = 0; rf < 4; ++rf)
      #pragma unroll
      for (int cf = 0; cf < 2; ++cf)
        #pragma unroll
        for (int r = 0; r < 4; ++r)
          h2[rf * 16 + rloc + r][wv * 32 + cf * 16 + l15] = (__bf16)sigm(acc[rf][cf][r]);
  }
  __syncthreads();

  // L2: N=256, K=128, no sigmoid, fp32 out
  {
    const __bf16* W = wb + DEC_W2_OFF + e * 32768;
    f32x4 acc[4][4];
    #pragma unroll
    for (int cf = 0; cf < 4; ++cf) {
      float bv = b2[e * 256 + wv * 64 + cf * 16 + l15];
      f32x4 bvv = {bv, bv, bv, bv};
      #pragma unroll
      for (int rf = 0; rf < 4; ++rf) acc[rf][cf] = bvv;
    }
    #pragma unroll
    for (int ks = 0; ks < 4; ++ks) {
      bf16x8 a[4], bb[4];
      #pragma unroll
      for (int rf = 0; rf < 4; ++rf) a[rf] = *(const bf16x8*)&h2[rf * 16 + l15][ks * 32 + hi8];
      #pragma unroll
      for (int cf = 0; cf < 4; ++cf)
        bb[cf] = *(const bf16x8*)(W + (size_t)(wv * 64 + cf * 16 + l15) * 128 + ks * 32 + hi8);
      #pragma unroll
      for (int rf = 0; rf < 4; ++rf)
        #pragma unroll
        for (int cf = 0; cf < 4; ++cf)
          acc[rf][cf] = MFMA16(a[rf], bb[cf], acc[rf][cf]);
    }
    #pragma unroll
    for (int rf = 0; rf < 4; ++rf)
      #pragma unroll
      for (int cf = 0; cf < 4; ++cf)
        #pragma unroll
        for (int r = 0; r < 4; ++r)
          out[(size_t)(m0 + rf * 16 + rloc + r) * 4096 + e * 256 + wv * 64 + cf * 16 + l15] =
              acc[rf][cf][r];
  }
}

// =============================== launcher ==================================
extern "C" void kernel_launch(void* const* d_in, const int* in_sizes, int n_in,
                              void* d_out, int out_size, void* d_ws, size_t ws_size,
                              hipStream_t stream) {
  (void)in_sizes; (void)n_in; (void)out_size; (void)ws_size;
  const float* x   = (const float*)d_in[0];
  const float* ew0 = (const float*)d_in[1];  const float* eb0 = (const float*)d_in[2];
  const float* ew1 = (const float*)d_in[3];  const float* eb1 = (const float*)d_in[4];
  const float* ew2 = (const float*)d_in[5];  const float* eb2 = (const float*)d_in[6];
  const float* dw0 = (const float*)d_in[7];  const float* db0 = (const float*)d_in[8];
  const float* dw1 = (const float*)d_in[9];  const float* db1 = (const float*)d_in[10];
  const float* dw2 = (const float*)d_in[11]; const float* db2 = (const float*)d_in[12];
  const float* cw[6]; const float* cb[6];
  for (int i = 0; i < 6; ++i) { cw[i] = (const float*)d_in[13 + 2 * i]; cb[i] = (const float*)d_in[14 + 2 * i]; }
  const float* xw[6]; const float* xb[6];
  for (int i = 0; i < 6; ++i) { xw[i] = (const float*)d_in[25 + 2 * i]; xb[i] = (const float*)d_in[26 + 2 * i]; }

  __bf16* wbuf   = (__bf16*)d_ws;
  __bf16* zstack = (__bf16*)((char*)d_ws + ZS_BYTES_OFF);  // z_stack, then z_stack_hat in-place
  float* out = (float*)d_out;

  prep_kernel<<<1024, 256, 0, stream>>>(ew0, ew1, ew2, dw0, dw1, dw2,
                                        cw[0], cw[1], cw[2], cw[3], cw[4], cw[5],
                                        xw[0], xw[1], xw[2], xw[3], xw[4], xw[5], wbuf);
  enc_kernel<<<dim3(512, 16), 256, 0, stream>>>(x, wbuf, eb0, eb1, eb2, zstack);
  MidBias mb = {cb[0], cb[1], cb[2], cb[3], cb[4], cb[5],
                xb[0], xb[1], xb[2], xb[3], xb[4], xb[5]};
  mid_kernel<<<512, 512, 0, stream>>>(zstack, wbuf, mb, zstack);
  dec_kernel<<<dim3(512, 16), 256, 0, stream>>>(zstack, wbuf, db0, db1, db2, out);
}

// Round 12
// 482.511 us; speedup vs baseline: 1.2639x; 1.2639x over previous
//
#include <hip/hip_runtime.h>

typedef __bf16 bf16x8 __attribute__((ext_vector_type(8)));
typedef __bf16 bf16x4 __attribute__((ext_vector_type(4)));
typedef float  f32x4  __attribute__((ext_vector_type(4)));

#define MFMA16(a, b, c) __builtin_amdgcn_mfma_f32_16x16x32_bf16((a), (b), (c), 0, 0, 0)

__device__ __forceinline__ float sigm(float x) { return 1.0f / (1.0f + __expf(-x)); }

// ---- packed bf16 weight layout (element offsets inside d_ws) ----
enum : int {
  ENC_W0_OFF  = 0,        // 16 x 128 x 256
  ENC_W1_OFF  = 524288,   // 16 x 64 x 128
  ENC_W2_OFF  = 655360,   // 16 x 32 x 64
  DEC_W0_OFF  = 688128,   // 16 x 64 x 32
  DEC_W1_OFF  = 720896,   // 16 x 128 x 64
  DEC_W2_OFF  = 851968,   // 16 x 256 x 128
  COMP_W0_OFF = 1376256,  // 256 x 512  (folded [z,z])
  COMP_W1_OFF = 1507328,  // 128 x 768
  COMP_W2_OFF = 1605632,  // 64 x 640
  COMP_W3_OFF = 1646592,  // 32 x 576
  COMP_W4_OFF = 1665024,  // 16 x 544
  COMP_W5_OFF = 1673728,  // 32 x 544  (528 padded to 544, pad = 0)
  DCMP_W0_OFF = 1691136,  // 256 x 32  (folded)
  DCMP_W1_OFF = 1699328,  // 128 x 288
  DCMP_W2_OFF = 1736192,  // 64 x 160
  DCMP_W3_OFF = 1746432,  // 32 x 96
  DCMP_W4_OFF = 1749504,  // 16 x 64
  DCMP_W5_OFF = 1750528,  // 512 x 64  (48 padded to 64, pad = 0)
  W_TOTAL     = 1783296,
};

#define ZS_BYTES_OFF (4u * 1024u * 1024u)  // z_stack, overwritten in-place by z_stack_hat

// =============================== weight prep ===============================
__global__ void prep_kernel(
    const float* __restrict__ ew0, const float* __restrict__ ew1, const float* __restrict__ ew2,
    const float* __restrict__ dw0, const float* __restrict__ dw1, const float* __restrict__ dw2,
    const float* __restrict__ cw0, const float* __restrict__ cw1, const float* __restrict__ cw2,
    const float* __restrict__ cw3, const float* __restrict__ cw4, const float* __restrict__ cw5,
    const float* __restrict__ xw0, const float* __restrict__ xw1, const float* __restrict__ xw2,
    const float* __restrict__ xw3, const float* __restrict__ xw4, const float* __restrict__ xw5,
    __bf16* __restrict__ wb)
{
  for (int i = blockIdx.x * blockDim.x + threadIdx.x; i < W_TOTAL; i += gridDim.x * blockDim.x) {
    float v;
    if      (i < ENC_W1_OFF)  v = ew0[i - ENC_W0_OFF];
    else if (i < ENC_W2_OFF)  v = ew1[i - ENC_W1_OFF];
    else if (i < DEC_W0_OFF)  v = ew2[i - ENC_W2_OFF];
    else if (i < DEC_W1_OFF)  v = dw0[i - DEC_W0_OFF];
    else if (i < DEC_W2_OFF)  v = dw1[i - DEC_W1_OFF];
    else if (i < COMP_W0_OFF) v = dw2[i - DEC_W2_OFF];
    else if (i < COMP_W1_OFF) { int t = i - COMP_W0_OFF; int o = t >> 9, c = t & 511;
                                v = cw0[o * 1024 + c] + cw0[o * 1024 + 512 + c]; }
    else if (i < COMP_W2_OFF) v = cw1[i - COMP_W1_OFF];
    else if (i < COMP_W3_OFF) v = cw2[i - COMP_W2_OFF];
    else if (i < COMP_W4_OFF) v = cw3[i - COMP_W3_OFF];
    else if (i < COMP_W5_OFF) v = cw4[i - COMP_W4_OFF];
    else if (i < DCMP_W0_OFF) { int t = i - COMP_W5_OFF; int o = t / 544, c = t % 544;
                                v = (c < 528) ? cw5[o * 528 + c] : 0.0f; }
    else if (i < DCMP_W1_OFF) { int t = i - DCMP_W0_OFF; int o = t >> 5, c = t & 31;
                                v = xw0[o * 64 + c] + xw0[o * 64 + 32 + c]; }
    else if (i < DCMP_W2_OFF) v = xw1[i - DCMP_W1_OFF];
    else if (i < DCMP_W3_OFF) v = xw2[i - DCMP_W2_OFF];
    else if (i < DCMP_W4_OFF) v = xw3[i - DCMP_W3_OFF];
    else if (i < DCMP_W5_OFF) v = xw4[i - DCMP_W4_OFF];
    else                      { int t = i - DCMP_W5_OFF; int o = t >> 6, c = t & 63;
                                v = (c < 48) ? xw5[o * 48 + c] : 0.0f; }
    wb[i] = (__bf16)v;
  }
}

// =============================== encoder ===================================
// R7 structure; single change: L0 x-tile staged as two 64x128 half-slabs with
// half-1's global loads issued BEFORE computing ks=0..3 on half-0 (latency
// hidden under 32 MFMAs + cross-block overlap). LDS 52.2 KB -> 3 blocks/CU.
__global__ __launch_bounds__(256, 3)
void enc_kernel(const float* __restrict__ x, const __bf16* __restrict__ wb,
                const float* __restrict__ b0, const float* __restrict__ b1,
                const float* __restrict__ b2, __bf16* __restrict__ zout)
{
  __shared__ __align__(16) char smem[52224];
  __bf16* xs0 = (__bf16*)smem;            // [64][136] cols 0..127, dead after L0
  __bf16* xs1 = (__bf16*)(smem + 17408);  // [64][136] cols 128..255
  __bf16* h1  = (__bf16*)(smem + 34816);  // [64][136]
  __bf16* h2  = (__bf16*)smem;            // [64][72], aliases xs0 (written after L1 sync)
  const int e = blockIdx.y;
  const int m0 = blockIdx.x * 64;
  const int tid = threadIdx.x;
  const int lane = tid & 63, wv = tid >> 6;
  const int l15 = lane & 15, hi8 = (lane >> 4) * 8, rloc = (lane >> 4) * 4;

  const float* xblk = x + (size_t)m0 * 4096 + e * 256;
  // thread t covers row r=idx>>5, float4 f=idx&31 within a 64x128 half-slab
  {
    float4 v[8];
    #pragma unroll
    for (int i = 0; i < 8; ++i) {
      int idx = tid + i * 256; int r = idx >> 5, f = idx & 31;
      v[i] = *(const float4*)(xblk + (size_t)r * 4096 + f * 4);
    }
    #pragma unroll
    for (int i = 0; i < 8; ++i) {
      int idx = tid + i * 256; int r = idx >> 5, f = idx & 31;
      bf16x4 o = {(__bf16)v[i].x, (__bf16)v[i].y, (__bf16)v[i].z, (__bf16)v[i].w};
      *(bf16x4*)&xs0[r * 136 + f * 4] = o;
    }
  }
  __syncthreads();

  // L0: N=128, K=256. wave covers cols [wv*32, wv*32+32).
  {
    const __bf16* W = wb + ENC_W0_OFF + e * 32768;
    f32x4 acc[4][2];
    #pragma unroll
    for (int cf = 0; cf < 2; ++cf) {
      float bv = b0[e * 128 + wv * 32 + cf * 16 + l15];
      f32x4 bvv = {bv, bv, bv, bv};
      #pragma unroll
      for (int rf = 0; rf < 4; ++rf) acc[rf][cf] = bvv;
    }
    // issue half-1 loads NOW; compute ks=0..3 on half-0 while they fly
    float4 v[8];
    #pragma unroll
    for (int i = 0; i < 8; ++i) {
      int idx = tid + i * 256; int r = idx >> 5, f = idx & 31;
      v[i] = *(const float4*)(xblk + 128 + (size_t)r * 4096 + f * 4);
    }
    #pragma unroll
    for (int ks = 0; ks < 4; ++ks) {
      bf16x8 a[4], bb[2];
      #pragma unroll
      for (int rf = 0; rf < 4; ++rf)
        a[rf] = *(const bf16x8*)&xs0[(rf * 16 + l15) * 136 + ks * 32 + hi8];
      #pragma unroll
      for (int cf = 0; cf < 2; ++cf)
        bb[cf] = *(const bf16x8*)(W + (size_t)(wv * 32 + cf * 16 + l15) * 256 + ks * 32 + hi8);
      #pragma unroll
      for (int rf = 0; rf < 4; ++rf)
        #pragma unroll
        for (int cf = 0; cf < 2; ++cf)
          acc[rf][cf] = MFMA16(a[rf], bb[cf], acc[rf][cf]);
    }
    // write half-1 (waits only on its own loads), then barrier
    #pragma unroll
    for (int i = 0; i < 8; ++i) {
      int idx = tid + i * 256; int r = idx >> 5, f = idx & 31;
      bf16x4 o = {(__bf16)v[i].x, (__bf16)v[i].y, (__bf16)v[i].z, (__bf16)v[i].w};
      *(bf16x4*)&xs1[r * 136 + f * 4] = o;
    }
    __syncthreads();
    #pragma unroll
    for (int ks = 4; ks < 8; ++ks) {
      bf16x8 a[4], bb[2];
      #pragma unroll
      for (int rf = 0; rf < 4; ++rf)
        a[rf] = *(const bf16x8*)&xs1[(rf * 16 + l15) * 136 + (ks - 4) * 32 + hi8];
      #pragma unroll
      for (int cf = 0; cf < 2; ++cf)
        bb[cf] = *(const bf16x8*)(W + (size_t)(wv * 32 + cf * 16 + l15) * 256 + ks * 32 + hi8);
      #pragma unroll
      for (int rf = 0; rf < 4; ++rf)
        #pragma unroll
        for (int cf = 0; cf < 2; ++cf)
          acc[rf][cf] = MFMA16(a[rf], bb[cf], acc[rf][cf]);
    }
    #pragma unroll
    for (int rf = 0; rf < 4; ++rf)
      #pragma unroll
      for (int cf = 0; cf < 2; ++cf)
        #pragma unroll
        for (int r = 0; r < 4; ++r)
          h1[(rf * 16 + rloc + r) * 136 + wv * 32 + cf * 16 + l15] = (__bf16)sigm(acc[rf][cf][r]);
  }
  __syncthreads();

  // L1: N=64, K=128. h2 overwrites the xs0 alias region (xs fully dead).
  {
    const __bf16* W = wb + ENC_W1_OFF + e * 8192;
    f32x4 acc[4];
    float bv = b1[e * 64 + wv * 16 + l15];
    f32x4 bvv = {bv, bv, bv, bv};
    #pragma unroll
    for (int rf = 0; rf < 4; ++rf) acc[rf] = bvv;
    #pragma unroll
    for (int ks = 0; ks < 4; ++ks) {
      bf16x8 a[4];
      #pragma unroll
      for (int rf = 0; rf < 4; ++rf) a[rf] = *(const bf16x8*)&h1[(rf * 16 + l15) * 136 + ks * 32 + hi8];
      bf16x8 bb = *(const bf16x8*)(W + (size_t)(wv * 16 + l15) * 128 + ks * 32 + hi8);
      #pragma unroll
      for (int rf = 0; rf < 4; ++rf) acc[rf] = MFMA16(a[rf], bb, acc[rf]);
    }
    #pragma unroll
    for (int rf = 0; rf < 4; ++rf)
      #pragma unroll
      for (int r = 0; r < 4; ++r)
        h2[(rf * 16 + rloc + r) * 72 + wv * 16 + l15] = (__bf16)sigm(acc[rf][r]);
  }
  __syncthreads();

  // L2: N=32, K=64, no sigmoid. waves 0,1 only.
  if (wv < 2) {
    const __bf16* W = wb + ENC_W2_OFF + e * 2048;
    f32x4 acc[4];
    float bv = b2[e * 32 + wv * 16 + l15];
    f32x4 bvv = {bv, bv, bv, bv};
    #pragma unroll
    for (int rf = 0; rf < 4; ++rf) acc[rf] = bvv;
    #pragma unroll
    for (int ks = 0; ks < 2; ++ks) {
      bf16x8 a[4];
      #pragma unroll
      for (int rf = 0; rf < 4; ++rf) a[rf] = *(const bf16x8*)&h2[(rf * 16 + l15) * 72 + ks * 32 + hi8];
      bf16x8 bb = *(const bf16x8*)(W + (size_t)(wv * 16 + l15) * 64 + ks * 32 + hi8);
      #pragma unroll
      for (int rf = 0; rf < 4; ++rf) acc[rf] = MFMA16(a[rf], bb, acc[rf]);
    }
    #pragma unroll
    for (int rf = 0; rf < 4; ++rf)
      #pragma unroll
      for (int r = 0; r < 4; ++r)
        zout[(size_t)(m0 + rf * 16 + rloc + r) * 512 + e * 32 + wv * 16 + l15] = (__bf16)acc[rf][r];
  }
}

// ==================== 8-wave residual layer, 64-row tile ===================
template<int NF, int KT, int ZKS, int ZLD, int SKS, int SLD, int DLD, bool SIG>
__device__ __forceinline__ void rlayer(const __bf16* __restrict__ W, const float* __restrict__ bias,
                                       const __bf16* __restrict__ zp, const __bf16* __restrict__ sp,
                                       __bf16* __restrict__ dst,
                                       int wv, int l15, int hi8, int rloc)
{
  constexpr int NJ = (NF >= 32) ? 4 : ((NF >= 16) ? 2 : 1);
  constexpr int NR = (NF >= 8) ? 4 : ((NF == 4) ? 2 : 1);
  int c0, row0;
  if constexpr (NF >= 8)       { c0 = wv;      row0 = 0; }
  else if constexpr (NF == 4)  { c0 = wv & 3;  row0 = (wv >> 2) * 32; }
  else if constexpr (NF == 2)  { c0 = wv & 1;  row0 = (wv >> 1) * 16; }
  else                         { if (wv >= 4) return; c0 = 0; row0 = wv * 16; }
  f32x4 acc[NR][NJ];
  #pragma unroll
  for (int j = 0; j < NJ; ++j) {
    float bv = bias[(c0 + 8 * j) * 16 + l15];
    f32x4 b4 = {bv, bv, bv, bv};
    #pragma unroll
    for (int rf = 0; rf < NR; ++rf) acc[rf][j] = b4;
  }
  #pragma unroll
  for (int ks = 0; ks < ZKS; ++ks) {
    bf16x8 a[NR];
    #pragma unroll
    for (int rf = 0; rf < NR; ++rf)
      a[rf] = *(const bf16x8*)&zp[(size_t)(row0 + rf * 16 + l15) * ZLD + ks * 32 + hi8];
    #pragma unroll
    for (int j = 0; j < NJ; ++j) {
      bf16x8 b = *(const bf16x8*)&W[(size_t)((c0 + 8 * j) * 16 + l15) * KT + ks * 32 + hi8];
      #pragma unroll
      for (int rf = 0; rf < NR; ++rf) acc[rf][j] = MFMA16(a[rf], b, acc[rf][j]);
    }
  }
  if constexpr (SKS > 0) {
    #pragma unroll
    for (int ks = 0; ks < SKS; ++ks) {
      bf16x8 a[NR];
      #pragma unroll
      for (int rf = 0; rf < NR; ++rf)
        a[rf] = *(const bf16x8*)&sp[(size_t)(row0 + rf * 16 + l15) * SLD + ks * 32 + hi8];
      #pragma unroll
      for (int j = 0; j < NJ; ++j) {
        bf16x8 b = *(const bf16x8*)&W[(size_t)((c0 + 8 * j) * 16 + l15) * KT + ZKS * 32 + ks * 32 + hi8];
        #pragma unroll
        for (int rf = 0; rf < NR; ++rf) acc[rf][j] = MFMA16(a[rf], b, acc[rf][j]);
      }
    }
  }
  #pragma unroll
  for (int j = 0; j < NJ; ++j)
    #pragma unroll
    for (int rf = 0; rf < NR; ++rf)
      #pragma unroll
      for (int r = 0; r < 4; ++r) {
        float v = acc[rf][j][r];
        dst[(size_t)(row0 + rf * 16 + rloc + r) * DLD + (c0 + 8 * j) * 16 + l15] =
            (__bf16)(SIG ? sigm(v) : v);
      }
}

// ===================== middle: comp + decomp fused (R10 verbatim) ==========
struct MidBias {
  const float *c0, *c1, *c2, *c3, *c4, *c5;
  const float *x0, *x1, *x2, *x3, *x4, *x5;
};

__global__ __launch_bounds__(512, 2)
void mid_kernel(const __bf16* __restrict__ zin, const __bf16* __restrict__ wb,
                MidBias mb, __bf16* __restrict__ zhout)
{
  __shared__ __bf16 zs[64 * 520];
  __shared__ __bf16 sA[64 * 264];
  __shared__ __bf16 sB[64 * 136];
  __shared__ __bf16 zsm[64 * 40];
  const int tid = threadIdx.x;
  const int wv = tid >> 6, lane = tid & 63;
  const int l15 = lane & 15, hi8 = (lane >> 4) * 8, rloc = (lane >> 4) * 4;
  const int m0 = blockIdx.x * 64;

  #pragma unroll
  for (int i = 0; i < 8; ++i) {
    int idx = tid + i * 512;
    int r = idx >> 6, c8 = (idx & 63) * 8;
    *(bf16x8*)&zs[r * 520 + c8] = *(const bf16x8*)(zin + (size_t)(m0 + r) * 512 + c8);
  }
  __syncthreads();
  // ---- compressor ----
  rlayer<16, 512, 16, 520, 0,   0, 264, true >(wb + COMP_W0_OFF, mb.c0, zs, nullptr, sA, wv, l15, hi8, rloc); __syncthreads();
  rlayer< 8, 768, 16, 520, 8, 264, 136, true >(wb + COMP_W1_OFF, mb.c1, zs, sA, sB, wv, l15, hi8, rloc); __syncthreads();
  rlayer< 4, 640, 16, 520, 4, 136, 264, true >(wb + COMP_W2_OFF, mb.c2, zs, sB, sA, wv, l15, hi8, rloc); __syncthreads();
  rlayer< 2, 576, 16, 520, 2, 264, 136, true >(wb + COMP_W3_OFF, mb.c3, zs, sA, sB, wv, l15, hi8, rloc); __syncthreads();
  rlayer< 1, 544, 16, 520, 1, 136, 264, true >(wb + COMP_W4_OFF, mb.c4, zs, sB, sA, wv, l15, hi8, rloc);
  for (int i = tid; i < 64 * 16; i += 512) sA[(i >> 4) * 264 + 16 + (i & 15)] = (__bf16)0.0f;
  __syncthreads();
  rlayer< 2, 544, 16, 520, 1, 264, 40, false>(wb + COMP_W5_OFF, mb.c5, zs, sA, zsm, wv, l15, hi8, rloc);
  __syncthreads();
  // ---- decompressor ----
  rlayer<16,  32, 1, 40, 0,   0, 264, true >(wb + DCMP_W0_OFF, mb.x0, zsm, nullptr, sA, wv, l15, hi8, rloc); __syncthreads();
  rlayer< 8, 288, 1, 40, 8, 264, 136, true >(wb + DCMP_W1_OFF, mb.x1, zsm, sA, sB, wv, l15, hi8, rloc); __syncthreads();
  rlayer< 4, 160, 1, 40, 4, 136, 264, true >(wb + DCMP_W2_OFF, mb.x2, zsm, sB, sA, wv, l15, hi8, rloc); __syncthreads();
  rlayer< 2,  96, 1, 40, 2, 264, 136, true >(wb + DCMP_W3_OFF, mb.x3, zsm, sA, sB, wv, l15, hi8, rloc); __syncthreads();
  rlayer< 1,  64, 1, 40, 1, 136, 264, true >(wb + DCMP_W4_OFF, mb.x4, zsm, sB, sA, wv, l15, hi8, rloc);
  for (int i = tid; i < 64 * 16; i += 512) sA[(i >> 4) * 264 + 16 + (i & 15)] = (__bf16)0.0f;
  __syncthreads();
  rlayer<32,  64, 1, 40, 1, 264, 512, false>(wb + DCMP_W5_OFF, mb.x5, zsm, sA,
                                             zhout + (size_t)m0 * 512, wv, l15, hi8, rloc);
}

// =============================== decoder (R7 verbatim) =====================
__global__ __launch_bounds__(256, 4)
void dec_kernel(const __bf16* __restrict__ zin, const __bf16* __restrict__ wb,
                const float* __restrict__ b0, const float* __restrict__ b1,
                const float* __restrict__ b2, float* __restrict__ out)
{
  __shared__ __bf16 zs[64][40];
  __shared__ __bf16 h1[64][72];
  __shared__ __bf16 h2[64][136];
  const int e = blockIdx.y;
  const int m0 = blockIdx.x * 64;
  const int tid = threadIdx.x;
  const int lane = tid & 63, wv = tid >> 6;
  const int l15 = lane & 15, hi8 = (lane >> 4) * 8, rloc = (lane >> 4) * 4;

  {
    int r = tid >> 2, c = (tid & 3) * 8;
    *(bf16x8*)&zs[r][c] = *(const bf16x8*)(zin + (size_t)(m0 + r) * 512 + e * 32 + c);
  }
  __syncthreads();

  // L0: N=64, K=32
  {
    const __bf16* W = wb + DEC_W0_OFF + e * 2048;
    f32x4 acc[4];
    float bv = b0[e * 64 + wv * 16 + l15];
    f32x4 bvv = {bv, bv, bv, bv};
    #pragma unroll
    for (int rf = 0; rf < 4; ++rf) acc[rf] = bvv;
    bf16x8 a[4];
    #pragma unroll
    for (int rf = 0; rf < 4; ++rf) a[rf] = *(const bf16x8*)&zs[rf * 16 + l15][hi8];
    bf16x8 bb = *(const bf16x8*)(W + (size_t)(wv * 16 + l15) * 32 + hi8);
    #pragma unroll
    for (int rf = 0; rf < 4; ++rf) acc[rf] = MFMA16(a[rf], bb, acc[rf]);
    #pragma unroll
    for (int rf = 0; rf < 4; ++rf)
      #pragma unroll
      for (int r = 0; r < 4; ++r)
        h1[rf * 16 + rloc + r][wv * 16 + l15] = (__bf16)sigm(acc[rf][r]);
  }
  __syncthreads();

  // L1: N=128, K=64
  {
    const __bf16* W = wb + DEC_W1_OFF + e * 8192;
    f32x4 acc[4][2];
    #pragma unroll
    for (int cf = 0; cf < 2; ++cf) {
      float bv = b1[e * 128 + wv * 32 + cf * 16 + l15];
      f32x4 bvv = {bv, bv, bv, bv};
      #pragma unroll
      for (int rf = 0; rf < 4; ++rf) acc[rf][cf] = bvv;
    }
    #pragma unroll
    for (int ks = 0; ks < 2; ++ks) {
      bf16x8 a[4], bb[2];
      #pragma unroll
      for (int rf = 0; rf < 4; ++rf) a[rf] = *(const bf16x8*)&h1[rf * 16 + l15][ks * 32 + hi8];
      #pragma unroll
      for (int cf = 0; cf < 2; ++cf)
        bb[cf] = *(const bf16x8*)(W + (size_t)(wv * 32 + cf * 16 + l15) * 64 + ks * 32 + hi8);
      #pragma unroll
      for (int rf = 0; rf < 4; ++rf)
        #pragma unroll
        for (int cf = 0; cf < 2; ++cf)
          acc[rf][cf] = MFMA16(a[rf], bb[cf], acc[rf][cf]);
    }
    #pragma unroll
    for (int rf = 0; rf < 4; ++rf)
      #pragma unroll
      for (int cf = 0; cf < 2; ++cf)
        #pragma unroll
        for (int r = 0; r < 4; ++r)
          h2[rf * 16 + rloc + r][wv * 32 + cf * 16 + l15] = (__bf16)sigm(acc[rf][cf][r]);
  }
  __syncthreads();

  // L2: N=256, K=128, no sigmoid, fp32 out
  {
    const __bf16* W = wb + DEC_W2_OFF + e * 32768;
    f32x4 acc[4][4];
    #pragma unroll
    for (int cf = 0; cf < 4; ++cf) {
      float bv = b2[e * 256 + wv * 64 + cf * 16 + l15];
      f32x4 bvv = {bv, bv, bv, bv};
      #pragma unroll
      for (int rf = 0; rf < 4; ++rf) acc[rf][cf] = bvv;
    }
    #pragma unroll
    for (int ks = 0; ks < 4; ++ks) {
      bf16x8 a[4], bb[4];
      #pragma unroll
      for (int rf = 0; rf < 4; ++rf) a[rf] = *(const bf16x8*)&h2[rf * 16 + l15][ks * 32 + hi8];
      #pragma unroll
      for (int cf = 0; cf < 4; ++cf)
        bb[cf] = *(const bf16x8*)(W + (size_t)(wv * 64 + cf * 16 + l15) * 128 + ks * 32 + hi8);
      #pragma unroll
      for (int rf = 0; rf < 4; ++rf)
        #pragma unroll
        for (int cf = 0; cf < 4; ++cf)
          acc[rf][cf] = MFMA16(a[rf], bb[cf], acc[rf][cf]);
    }
    #pragma unroll
    for (int rf = 0; rf < 4; ++rf)
      #pragma unroll
      for (int cf = 0; cf < 4; ++cf)
        #pragma unroll
        for (int r = 0; r < 4; ++r)
          out[(size_t)(m0 + rf * 16 + rloc + r) * 4096 + e * 256 + wv * 64 + cf * 16 + l15] =
              acc[rf][cf][r];
  }
}

// =============================== launcher ==================================
extern "C" void kernel_launch(void* const* d_in, const int* in_sizes, int n_in,
                              void* d_out, int out_size, void* d_ws, size_t ws_size,
                              hipStream_t stream) {
  (void)in_sizes; (void)n_in; (void)out_size; (void)ws_size;
  const float* x   = (const float*)d_in[0];
  const float* ew0 = (const float*)d_in[1];  const float* eb0 = (const float*)d_in[2];
  const float* ew1 = (const float*)d_in[3];  const float* eb1 = (const float*)d_in[4];
  const float* ew2 = (const float*)d_in[5];  const float* eb2 = (const float*)d_in[6];
  const float* dw0 = (const float*)d_in[7];  const float* db0 = (const float*)d_in[8];
  const float* dw1 = (const float*)d_in[9];  const float* db1 = (const float*)d_in[10];
  const float* dw2 = (const float*)d_in[11]; const float* db2 = (const float*)d_in[12];
  const float* cw[6]; const float* cb[6];
  for (int i = 0; i < 6; ++i) { cw[i] = (const float*)d_in[13 + 2 * i]; cb[i] = (const float*)d_in[14 + 2 * i]; }
  const float* xw[6]; const float* xb[6];
  for (int i = 0; i < 6; ++i) { xw[i] = (const float*)d_in[25 + 2 * i]; xb[i] = (const float*)d_in[26 + 2 * i]; }

  __bf16* wbuf   = (__bf16*)d_ws;
  __bf16* zstack = (__bf16*)((char*)d_ws + ZS_BYTES_OFF);  // z_stack, then z_stack_hat in-place
  float* out = (float*)d_out;

  prep_kernel<<<1024, 256, 0, stream>>>(ew0, ew1, ew2, dw0, dw1, dw2,
                                        cw[0], cw[1], cw[2], cw[3], cw[4], cw[5],
                                        xw[0], xw[1], xw[2], xw[3], xw[4], xw[5], wbuf);
  enc_kernel<<<dim3(512, 16), 256, 0, stream>>>(x, wbuf, eb0, eb1, eb2, zstack);
  MidBias mb = {cb[0], cb[1], cb[2], cb[3], cb[4], cb[5],
                xb[0], xb[1], xb[2], xb[3], xb[4], xb[5]};
  mid_kernel<<<512, 512, 0, stream>>>(zstack, wbuf, mb, zstack);
  dec_kernel<<<dim3(512, 16), 256, 0, stream>>>(zstack, wbuf, db0, db1, db2, out);
}

// Round 13
// 396.643 us; speedup vs baseline: 1.5375x; 1.2165x over previous
//
#include <hip/hip_runtime.h>

typedef __bf16 bf16x8 __attribute__((ext_vector_type(8)));
typedef __bf16 bf16x4 __attribute__((ext_vector_type(4)));
typedef float  f32x4  __attribute__((ext_vector_type(4)));

#define MFMA16(a, b, c) __builtin_amdgcn_mfma_f32_16x16x32_bf16((a), (b), (c), 0, 0, 0)

__device__ __forceinline__ float sigm(float x) { return 1.0f / (1.0f + __expf(-x)); }

// ---- packed bf16 weight layout (element offsets inside d_ws) ----
enum : int {
  ENC_W0_OFF  = 0,        // 16 x 128 x 256
  ENC_W1_OFF  = 524288,   // 16 x 64 x 128
  ENC_W2_OFF  = 655360,   // 16 x 32 x 64
  DEC_W0_OFF  = 688128,   // 16 x 64 x 32
  DEC_W1_OFF  = 720896,   // 16 x 128 x 64
  DEC_W2_OFF  = 851968,   // 16 x 256 x 128
  COMP_W0_OFF = 1376256,  // 256 x 512  (folded [z,z])
  COMP_W1_OFF = 1507328,  // 128 x 768
  COMP_W2_OFF = 1605632,  // 64 x 640
  COMP_W3_OFF = 1646592,  // 32 x 576
  COMP_W4_OFF = 1665024,  // 16 x 544
  COMP_W5_OFF = 1673728,  // 32 x 544  (528 padded to 544, pad = 0)
  DCMP_W0_OFF = 1691136,  // 256 x 32  (folded)
  DCMP_W1_OFF = 1699328,  // 128 x 288
  DCMP_W2_OFF = 1736192,  // 64 x 160
  DCMP_W3_OFF = 1746432,  // 32 x 96
  DCMP_W4_OFF = 1749504,  // 16 x 64
  DCMP_W5_OFF = 1750528,  // 512 x 64  (48 padded to 64, pad = 0)
  W_TOTAL     = 1783296,
};

#define ZS_BYTES_OFF (4u * 1024u * 1024u)  // z_stack, overwritten in-place by z_stack_hat

// =============================== weight prep ===============================
__global__ void prep_kernel(
    const float* __restrict__ ew0, const float* __restrict__ ew1, const float* __restrict__ ew2,
    const float* __restrict__ dw0, const float* __restrict__ dw1, const float* __restrict__ dw2,
    const float* __restrict__ cw0, const float* __restrict__ cw1, const float* __restrict__ cw2,
    const float* __restrict__ cw3, const float* __restrict__ cw4, const float* __restrict__ cw5,
    const float* __restrict__ xw0, const float* __restrict__ xw1, const float* __restrict__ xw2,
    const float* __restrict__ xw3, const float* __restrict__ xw4, const float* __restrict__ xw5,
    __bf16* __restrict__ wb)
{
  for (int i = blockIdx.x * blockDim.x + threadIdx.x; i < W_TOTAL; i += gridDim.x * blockDim.x) {
    float v;
    if      (i < ENC_W1_OFF)  v = ew0[i - ENC_W0_OFF];
    else if (i < ENC_W2_OFF)  v = ew1[i - ENC_W1_OFF];
    else if (i < DEC_W0_OFF)  v = ew2[i - ENC_W2_OFF];
    else if (i < DEC_W1_OFF)  v = dw0[i - DEC_W0_OFF];
    else if (i < DEC_W2_OFF)  v = dw1[i - DEC_W1_OFF];
    else if (i < COMP_W0_OFF) v = dw2[i - DEC_W2_OFF];
    else if (i < COMP_W1_OFF) { int t = i - COMP_W0_OFF; int o = t >> 9, c = t & 511;
                                v = cw0[o * 1024 + c] + cw0[o * 1024 + 512 + c]; }
    else if (i < COMP_W2_OFF) v = cw1[i - COMP_W1_OFF];
    else if (i < COMP_W3_OFF) v = cw2[i - COMP_W2_OFF];
    else if (i < COMP_W4_OFF) v = cw3[i - COMP_W3_OFF];
    else if (i < COMP_W5_OFF) v = cw4[i - COMP_W4_OFF];
    else if (i < DCMP_W0_OFF) { int t = i - COMP_W5_OFF; int o = t / 544, c = t % 544;
                                v = (c < 528) ? cw5[o * 528 + c] : 0.0f; }
    else if (i < DCMP_W1_OFF) { int t = i - DCMP_W0_OFF; int o = t >> 5, c = t & 31;
                                v = xw0[o * 64 + c] + xw0[o * 64 + 32 + c]; }
    else if (i < DCMP_W2_OFF) v = xw1[i - DCMP_W1_OFF];
    else if (i < DCMP_W3_OFF) v = xw2[i - DCMP_W2_OFF];
    else if (i < DCMP_W4_OFF) v = xw3[i - DCMP_W3_OFF];
    else if (i < DCMP_W5_OFF) v = xw4[i - DCMP_W4_OFF];
    else                      { int t = i - DCMP_W5_OFF; int o = t >> 6, c = t & 63;
                                v = (c < 48) ? xw5[o * 48 + c] : 0.0f; }
    wb[i] = (__bf16)v;
  }
}

// =============================== encoder ===================================
// R7 inner structure; single change: grid is (e=16, m=512) so the 16
// temporally-adjacent blocks (same m-tile, all e) touch one contiguous 1 MB
// row-block of x -> DRAM page + L2 locality. LDS 50 KB -> 3 blocks/CU.
__global__ __launch_bounds__(256, 3)
void enc_kernel(const float* __restrict__ x, const __bf16* __restrict__ wb,
                const float* __restrict__ b0, const float* __restrict__ b1,
                const float* __restrict__ b2, __bf16* __restrict__ zout)
{
  __shared__ __align__(16) char smem[51200];
  __bf16* xs = (__bf16*)smem;            // [64][264], dead after L0
  __bf16* h1 = (__bf16*)(smem + 33792);  // [64][136]
  __bf16* h2 = (__bf16*)smem;            // [64][72], aliases xs
  const int e = blockIdx.x;              // e-major dispatch
  const int m0 = blockIdx.y * 64;
  const int tid = threadIdx.x;
  const int lane = tid & 63, wv = tid >> 6;
  const int l15 = lane & 15, hi8 = (lane >> 4) * 8, rloc = (lane >> 4) * 4;

  const float* xblk = x + (size_t)m0 * 4096 + e * 256;
  #pragma unroll
  for (int i = 0; i < 16; ++i) {
    int idx = tid + i * 256;
    int r = idx >> 6, c4 = (idx & 63) * 4;
    float4 v = *(const float4*)(xblk + (size_t)r * 4096 + c4);
    bf16x4 o = { (__bf16)v.x, (__bf16)v.y, (__bf16)v.z, (__bf16)v.w };
    *(bf16x4*)&xs[r * 264 + c4] = o;
  }
  __syncthreads();

  // L0: N=128, K=256. wave covers cols [wv*32, wv*32+32)
  {
    const __bf16* W = wb + ENC_W0_OFF + e * 32768;
    f32x4 acc[4][2];
    #pragma unroll
    for (int cf = 0; cf < 2; ++cf) {
      float bv = b0[e * 128 + wv * 32 + cf * 16 + l15];
      f32x4 bvv = {bv, bv, bv, bv};
      #pragma unroll
      for (int rf = 0; rf < 4; ++rf) acc[rf][cf] = bvv;
    }
    #pragma unroll
    for (int ks = 0; ks < 8; ++ks) {
      bf16x8 a[4], bb[2];
      #pragma unroll
      for (int rf = 0; rf < 4; ++rf) a[rf] = *(const bf16x8*)&xs[(rf * 16 + l15) * 264 + ks * 32 + hi8];
      #pragma unroll
      for (int cf = 0; cf < 2; ++cf)
        bb[cf] = *(const bf16x8*)(W + (size_t)(wv * 32 + cf * 16 + l15) * 256 + ks * 32 + hi8);
      #pragma unroll
      for (int rf = 0; rf < 4; ++rf)
        #pragma unroll
        for (int cf = 0; cf < 2; ++cf)
          acc[rf][cf] = MFMA16(a[rf], bb[cf], acc[rf][cf]);
    }
    #pragma unroll
    for (int rf = 0; rf < 4; ++rf)
      #pragma unroll
      for (int cf = 0; cf < 2; ++cf)
        #pragma unroll
        for (int r = 0; r < 4; ++r)
          h1[(rf * 16 + rloc + r) * 136 + wv * 32 + cf * 16 + l15] = (__bf16)sigm(acc[rf][cf][r]);
  }
  __syncthreads();

  // L1: N=64, K=128. h2 overwrites the xs alias region (xs fully dead).
  {
    const __bf16* W = wb + ENC_W1_OFF + e * 8192;
    f32x4 acc[4];
    float bv = b1[e * 64 + wv * 16 + l15];
    f32x4 bvv = {bv, bv, bv, bv};
    #pragma unroll
    for (int rf = 0; rf < 4; ++rf) acc[rf] = bvv;
    #pragma unroll
    for (int ks = 0; ks < 4; ++ks) {
      bf16x8 a[4];
      #pragma unroll
      for (int rf = 0; rf < 4; ++rf) a[rf] = *(const bf16x8*)&h1[(rf * 16 + l15) * 136 + ks * 32 + hi8];
      bf16x8 bb = *(const bf16x8*)(W + (size_t)(wv * 16 + l15) * 128 + ks * 32 + hi8);
      #pragma unroll
      for (int rf = 0; rf < 4; ++rf) acc[rf] = MFMA16(a[rf], bb, acc[rf]);
    }
    #pragma unroll
    for (int rf = 0; rf < 4; ++rf)
      #pragma unroll
      for (int r = 0; r < 4; ++r)
        h2[(rf * 16 + rloc + r) * 72 + wv * 16 + l15] = (__bf16)sigm(acc[rf][r]);
  }
  __syncthreads();

  // L2: N=32, K=64, no sigmoid. waves 0,1 only.
  if (wv < 2) {
    const __bf16* W = wb + ENC_W2_OFF + e * 2048;
    f32x4 acc[4];
    float bv = b2[e * 32 + wv * 16 + l15];
    f32x4 bvv = {bv, bv, bv, bv};
    #pragma unroll
    for (int rf = 0; rf < 4; ++rf) acc[rf] = bvv;
    #pragma unroll
    for (int ks = 0; ks < 2; ++ks) {
      bf16x8 a[4];
      #pragma unroll
      for (int rf = 0; rf < 4; ++rf) a[rf] = *(const bf16x8*)&h2[(rf * 16 + l15) * 72 + ks * 32 + hi8];
      bf16x8 bb = *(const bf16x8*)(W + (size_t)(wv * 16 + l15) * 64 + ks * 32 + hi8);
      #pragma unroll
      for (int rf = 0; rf < 4; ++rf) acc[rf] = MFMA16(a[rf], bb, acc[rf]);
    }
    #pragma unroll
    for (int rf = 0; rf < 4; ++rf)
      #pragma unroll
      for (int r = 0; r < 4; ++r)
        zout[(size_t)(m0 + rf * 16 + rloc + r) * 512 + e * 32 + wv * 16 + l15] = (__bf16)acc[rf][r];
  }
}

// ==================== 8-wave residual layer, 64-row tile ===================
template<int NF, int KT, int ZKS, int ZLD, int SKS, int SLD, int DLD, bool SIG>
__device__ __forceinline__ void rlayer(const __bf16* __restrict__ W, const float* __restrict__ bias,
                                       const __bf16* __restrict__ zp, const __bf16* __restrict__ sp,
                                       __bf16* __restrict__ dst,
                                       int wv, int l15, int hi8, int rloc)
{
  constexpr int NJ = (NF >= 32) ? 4 : ((NF >= 16) ? 2 : 1);
  constexpr int NR = (NF >= 8) ? 4 : ((NF == 4) ? 2 : 1);
  int c0, row0;
  if constexpr (NF >= 8)       { c0 = wv;      row0 = 0; }
  else if constexpr (NF == 4)  { c0 = wv & 3;  row0 = (wv >> 2) * 32; }
  else if constexpr (NF == 2)  { c0 = wv & 1;  row0 = (wv >> 1) * 16; }
  else                         { if (wv >= 4) return; c0 = 0; row0 = wv * 16; }
  f32x4 acc[NR][NJ];
  #pragma unroll
  for (int j = 0; j < NJ; ++j) {
    float bv = bias[(c0 + 8 * j) * 16 + l15];
    f32x4 b4 = {bv, bv, bv, bv};
    #pragma unroll
    for (int rf = 0; rf < NR; ++rf) acc[rf][j] = b4;
  }
  #pragma unroll
  for (int ks = 0; ks < ZKS; ++ks) {
    bf16x8 a[NR];
    #pragma unroll
    for (int rf = 0; rf < NR; ++rf)
      a[rf] = *(const bf16x8*)&zp[(size_t)(row0 + rf * 16 + l15) * ZLD + ks * 32 + hi8];
    #pragma unroll
    for (int j = 0; j < NJ; ++j) {
      bf16x8 b = *(const bf16x8*)&W[(size_t)((c0 + 8 * j) * 16 + l15) * KT + ks * 32 + hi8];
      #pragma unroll
      for (int rf = 0; rf < NR; ++rf) acc[rf][j] = MFMA16(a[rf], b, acc[rf][j]);
    }
  }
  if constexpr (SKS > 0) {
    #pragma unroll
    for (int ks = 0; ks < SKS; ++ks) {
      bf16x8 a[NR];
      #pragma unroll
      for (int rf = 0; rf < NR; ++rf)
        a[rf] = *(const bf16x8*)&sp[(size_t)(row0 + rf * 16 + l15) * SLD + ks * 32 + hi8];
      #pragma unroll
      for (int j = 0; j < NJ; ++j) {
        bf16x8 b = *(const bf16x8*)&W[(size_t)((c0 + 8 * j) * 16 + l15) * KT + ZKS * 32 + ks * 32 + hi8];
        #pragma unroll
        for (int rf = 0; rf < NR; ++rf) acc[rf][j] = MFMA16(a[rf], b, acc[rf][j]);
      }
    }
  }
  #pragma unroll
  for (int j = 0; j < NJ; ++j)
    #pragma unroll
    for (int rf = 0; rf < NR; ++rf)
      #pragma unroll
      for (int r = 0; r < 4; ++r) {
        float v = acc[rf][j][r];
        dst[(size_t)(row0 + rf * 16 + rloc + r) * DLD + (c0 + 8 * j) * 16 + l15] =
            (__bf16)(SIG ? sigm(v) : v);
      }
}

// ===================== middle: comp + decomp fused (R10 verbatim) ==========
struct MidBias {
  const float *c0, *c1, *c2, *c3, *c4, *c5;
  const float *x0, *x1, *x2, *x3, *x4, *x5;
};

__global__ __launch_bounds__(512, 2)
void mid_kernel(const __bf16* __restrict__ zin, const __bf16* __restrict__ wb,
                MidBias mb, __bf16* __restrict__ zhout)
{
  __shared__ __bf16 zs[64 * 520];
  __shared__ __bf16 sA[64 * 264];
  __shared__ __bf16 sB[64 * 136];
  __shared__ __bf16 zsm[64 * 40];
  const int tid = threadIdx.x;
  const int wv = tid >> 6, lane = tid & 63;
  const int l15 = lane & 15, hi8 = (lane >> 4) * 8, rloc = (lane >> 4) * 4;
  const int m0 = blockIdx.x * 64;

  #pragma unroll
  for (int i = 0; i < 8; ++i) {
    int idx = tid + i * 512;
    int r = idx >> 6, c8 = (idx & 63) * 8;
    *(bf16x8*)&zs[r * 520 + c8] = *(const bf16x8*)(zin + (size_t)(m0 + r) * 512 + c8);
  }
  __syncthreads();
  // ---- compressor ----
  rlayer<16, 512, 16, 520, 0,   0, 264, true >(wb + COMP_W0_OFF, mb.c0, zs, nullptr, sA, wv, l15, hi8, rloc); __syncthreads();
  rlayer< 8, 768, 16, 520, 8, 264, 136, true >(wb + COMP_W1_OFF, mb.c1, zs, sA, sB, wv, l15, hi8, rloc); __syncthreads();
  rlayer< 4, 640, 16, 520, 4, 136, 264, true >(wb + COMP_W2_OFF, mb.c2, zs, sB, sA, wv, l15, hi8, rloc); __syncthreads();
  rlayer< 2, 576, 16, 520, 2, 264, 136, true >(wb + COMP_W3_OFF, mb.c3, zs, sA, sB, wv, l15, hi8, rloc); __syncthreads();
  rlayer< 1, 544, 16, 520, 1, 136, 264, true >(wb + COMP_W4_OFF, mb.c4, zs, sB, sA, wv, l15, hi8, rloc);
  for (int i = tid; i < 64 * 16; i += 512) sA[(i >> 4) * 264 + 16 + (i & 15)] = (__bf16)0.0f;
  __syncthreads();
  rlayer< 2, 544, 16, 520, 1, 264, 40, false>(wb + COMP_W5_OFF, mb.c5, zs, sA, zsm, wv, l15, hi8, rloc);
  __syncthreads();
  // ---- decompressor ----
  rlayer<16,  32, 1, 40, 0,   0, 264, true >(wb + DCMP_W0_OFF, mb.x0, zsm, nullptr, sA, wv, l15, hi8, rloc); __syncthreads();
  rlayer< 8, 288, 1, 40, 8, 264, 136, true >(wb + DCMP_W1_OFF, mb.x1, zsm, sA, sB, wv, l15, hi8, rloc); __syncthreads();
  rlayer< 4, 160, 1, 40, 4, 136, 264, true >(wb + DCMP_W2_OFF, mb.x2, zsm, sB, sA, wv, l15, hi8, rloc); __syncthreads();
  rlayer< 2,  96, 1, 40, 2, 264, 136, true >(wb + DCMP_W3_OFF, mb.x3, zsm, sA, sB, wv, l15, hi8, rloc); __syncthreads();
  rlayer< 1,  64, 1, 40, 1, 136, 264, true >(wb + DCMP_W4_OFF, mb.x4, zsm, sB, sA, wv, l15, hi8, rloc);
  for (int i = tid; i < 64 * 16; i += 512) sA[(i >> 4) * 264 + 16 + (i & 15)] = (__bf16)0.0f;
  __syncthreads();
  rlayer<32,  64, 1, 40, 1, 264, 512, false>(wb + DCMP_W5_OFF, mb.x5, zsm, sA,
                                             zhout + (size_t)m0 * 512, wv, l15, hi8, rloc);
}

// =============================== decoder ===================================
// R7 inner structure; single change: grid (e=16, m=512) so adjacent blocks
// write adjacent 1 KB out-slices of the same 64 rows (page/L2 locality).
__global__ __launch_bounds__(256, 4)
void dec_kernel(const __bf16* __restrict__ zin, const __bf16* __restrict__ wb,
                const float* __restrict__ b0, const float* __restrict__ b1,
                const float* __restrict__ b2, float* __restrict__ out)
{
  __shared__ __bf16 zs[64][40];
  __shared__ __bf16 h1[64][72];
  __shared__ __bf16 h2[64][136];
  const int e = blockIdx.x;              // e-major dispatch
  const int m0 = blockIdx.y * 64;
  const int tid = threadIdx.x;
  const int lane = tid & 63, wv = tid >> 6;
  const int l15 = lane & 15, hi8 = (lane >> 4) * 8, rloc = (lane >> 4) * 4;

  {
    int r = tid >> 2, c = (tid & 3) * 8;
    *(bf16x8*)&zs[r][c] = *(const bf16x8*)(zin + (size_t)(m0 + r) * 512 + e * 32 + c);
  }
  __syncthreads();

  // L0: N=64, K=32
  {
    const __bf16* W = wb + DEC_W0_OFF + e * 2048;
    f32x4 acc[4];
    float bv = b0[e * 64 + wv * 16 + l15];
    f32x4 bvv = {bv, bv, bv, bv};
    #pragma unroll
    for (int rf = 0; rf < 4; ++rf) acc[rf] = bvv;
    bf16x8 a[4];
    #pragma unroll
    for (int rf = 0; rf < 4; ++rf) a[rf] = *(const bf16x8*)&zs[rf * 16 + l15][hi8];
    bf16x8 bb = *(const bf16x8*)(W + (size_t)(wv * 16 + l15) * 32 + hi8);
    #pragma unroll
    for (int rf = 0; rf < 4; ++rf) acc[rf] = MFMA16(a[rf], bb, acc[rf]);
    #pragma unroll
    for (int rf = 0; rf < 4; ++rf)
      #pragma unroll
      for (int r = 0; r < 4; ++r)
        h1[rf * 16 + rloc + r][wv * 16 + l15] = (__bf16)sigm(acc[rf][r]);
  }
  __syncthreads();

  // L1: N=128, K=64
  {
    const __bf16* W = wb + DEC_W1_OFF + e * 8192;
    f32x4 acc[4][2];
    #pragma unroll
    for (int cf = 0; cf < 2; ++cf) {
      float bv = b1[e * 128 + wv * 32 + cf * 16 + l15];
      f32x4 bvv = {bv, bv, bv, bv};
      #pragma unroll
      for (int rf = 0; rf < 4; ++rf) acc[rf][cf] = bvv;
    }
    #pragma unroll
    for (int ks = 0; ks < 2; ++ks) {
      bf16x8 a[4], bb[2];
      #pragma unroll
      for (int rf = 0; rf < 4; ++rf) a[rf] = *(const bf16x8*)&h1[rf * 16 + l15][ks * 32 + hi8];
      #pragma unroll
      for (int cf = 0; cf < 2; ++cf)
        bb[cf] = *(const bf16x8*)(W + (size_t)(wv * 32 + cf * 16 + l15) * 64 + ks * 32 + hi8);
      #pragma unroll
      for (int rf = 0; rf < 4; ++rf)
        #pragma unroll
        for (int cf = 0; cf < 2; ++cf)
          acc[rf][cf] = MFMA16(a[rf], bb[cf], acc[rf][cf]);
    }
    #pragma unroll
    for (int rf = 0; rf < 4; ++rf)
      #pragma unroll
      for (int cf = 0; cf < 2; ++cf)
        #pragma unroll
        for (int r = 0; r < 4; ++r)
          h2[rf * 16 + rloc + r][wv * 32 + cf * 16 + l15] = (__bf16)sigm(acc[rf][cf][r]);
  }
  __syncthreads();

  // L2: N=256, K=128, no sigmoid, fp32 out
  {
    const __bf16* W = wb + DEC_W2_OFF + e * 32768;
    f32x4 acc[4][4];
    #pragma unroll
    for (int cf = 0; cf < 4; ++cf) {
      float bv = b2[e * 256 + wv * 64 + cf * 16 + l15];
      f32x4 bvv = {bv, bv, bv, bv};
      #pragma unroll
      for (int rf = 0; rf < 4; ++rf) acc[rf][cf] = bvv;
    }
    #pragma unroll
    for (int ks = 0; ks < 4; ++ks) {
      bf16x8 a[4], bb[4];
      #pragma unroll
      for (int rf = 0; rf < 4; ++rf) a[rf] = *(const bf16x8*)&h2[rf * 16 + l15][ks * 32 + hi8];
      #pragma unroll
      for (int cf = 0; cf < 4; ++cf)
        bb[cf] = *(const bf16x8*)(W + (size_t)(wv * 64 + cf * 16 + l15) * 128 + ks * 32 + hi8);
      #pragma unroll
      for (int rf = 0; rf < 4; ++rf)
        #pragma unroll
        for (int cf = 0; cf < 4; ++cf)
          acc[rf][cf] = MFMA16(a[rf], bb[cf], acc[rf][cf]);
    }
    #pragma unroll
    for (int rf = 0; rf < 4; ++rf)
      #pragma unroll
      for (int cf = 0; cf < 4; ++cf)
        #pragma unroll
        for (int r = 0; r < 4; ++r)
          out[(size_t)(m0 + rf * 16 + rloc + r) * 4096 + e * 256 + wv * 64 + cf * 16 + l15] =
              acc[rf][cf][r];
  }
}

// =============================== launcher ==================================
extern "C" void kernel_launch(void* const* d_in, const int* in_sizes, int n_in,
                              void* d_out, int out_size, void* d_ws, size_t ws_size,
                              hipStream_t stream) {
  (void)in_sizes; (void)n_in; (void)out_size; (void)ws_size;
  const float* x   = (const float*)d_in[0];
  const float* ew0 = (const float*)d_in[1];  const float* eb0 = (const float*)d_in[2];
  const float* ew1 = (const float*)d_in[3];  const float* eb1 = (const float*)d_in[4];
  const float* ew2 = (const float*)d_in[5];  const float* eb2 = (const float*)d_in[6];
  const float* dw0 = (const float*)d_in[7];  const float* db0 = (const float*)d_in[8];
  const float* dw1 = (const float*)d_in[9];  const float* db1 = (const float*)d_in[10];
  const float* dw2 = (const float*)d_in[11]; const float* db2 = (const float*)d_in[12];
  const float* cw[6]; const float* cb[6];
  for (int i = 0; i < 6; ++i) { cw[i] = (const float*)d_in[13 + 2 * i]; cb[i] = (const float*)d_in[14 + 2 * i]; }
  const float* xw[6]; const float* xb[6];
  for (int i = 0; i < 6; ++i) { xw[i] = (const float*)d_in[25 + 2 * i]; xb[i] = (const float*)d_in[26 + 2 * i]; }

  __bf16* wbuf   = (__bf16*)d_ws;
  __bf16* zstack = (__bf16*)((char*)d_ws + ZS_BYTES_OFF);  // z_stack, then z_stack_hat in-place
  float* out = (float*)d_out;

  prep_kernel<<<1024, 256, 0, stream>>>(ew0, ew1, ew2, dw0, dw1, dw2,
                                        cw[0], cw[1], cw[2], cw[3], cw[4], cw[5],
                                        xw[0], xw[1], xw[2], xw[3], xw[4], xw[5], wbuf);
  enc_kernel<<<dim3(16, 512), 256, 0, stream>>>(x, wbuf, eb0, eb1, eb2, zstack);
  MidBias mb = {cb[0], cb[1], cb[2], cb[3], cb[4], cb[5],
                xb[0], xb[1], xb[2], xb[3], xb[4], xb[5]};
  mid_kernel<<<512, 512, 0, stream>>>(zstack, wbuf, mb, zstack);
  dec_kernel<<<dim3(16, 512), 256, 0, stream>>>(zstack, wbuf, db0, db1, db2, out);
}

// Round 14
// 345.276 us; speedup vs baseline: 1.7663x; 1.1488x over previous
//
#include <hip/hip_runtime.h>

typedef __bf16 bf16x8 __attribute__((ext_vector_type(8)));
typedef __bf16 bf16x4 __attribute__((ext_vector_type(4)));
typedef float  f32x4  __attribute__((ext_vector_type(4)));

#define MFMA16(a, b, c) __builtin_amdgcn_mfma_f32_16x16x32_bf16((a), (b), (c), 0, 0, 0)

__device__ __forceinline__ float sigm(float x) { return 1.0f / (1.0f + __expf(-x)); }

// ---- packed bf16 weight layout (element offsets inside d_ws) ----
// Each matrix is stored FRAGMENT-MAJOR: fragment (kf, c) = 512 contiguous
// elements; lane L's bf16x8 B-operand at ((kf*NC16 + c)*64 + L)*8.
// Content: lane L, elem j = W[c*16 + (L&15)][kf*32 + (L>>4)*8 + j].
enum : int {
  ENC_W0_OFF  = 0,        // 16 x (128 x 256)
  ENC_W1_OFF  = 524288,   // 16 x (64 x 128)
  ENC_W2_OFF  = 655360,   // 16 x (32 x 64)
  DEC_W0_OFF  = 688128,   // 16 x (64 x 32)
  DEC_W1_OFF  = 720896,   // 16 x (128 x 64)
  DEC_W2_OFF  = 851968,   // 16 x (256 x 128)
  COMP_W0_OFF = 1376256,  // 256 x 512  (folded [z,z])
  COMP_W1_OFF = 1507328,  // 128 x 768
  COMP_W2_OFF = 1605632,  // 64 x 640
  COMP_W3_OFF = 1646592,  // 32 x 576
  COMP_W4_OFF = 1665024,  // 16 x 544
  COMP_W5_OFF = 1673728,  // 32 x 544  (528 padded to 544, pad = 0)
  DCMP_W0_OFF = 1691136,  // 256 x 32  (folded)
  DCMP_W1_OFF = 1699328,  // 128 x 288
  DCMP_W2_OFF = 1736192,  // 64 x 160
  DCMP_W3_OFF = 1746432,  // 32 x 96
  DCMP_W4_OFF = 1749504,  // 16 x 64
  DCMP_W5_OFF = 1750528,  // 512 x 64  (48 padded to 64, pad = 0)
  W_TOTAL     = 1783296,
};

#define ZS_BYTES_OFF (4u * 1024u * 1024u)  // z_stack, overwritten in-place by z_stack_hat

// lane-contiguous B-fragment load (1 KB per fragment, fully coalesced)
__device__ __forceinline__ bf16x8 ldB(const __bf16* __restrict__ Wp, int nc16, int kf, int c, int lane) {
  return *(const bf16x8*)(Wp + (((size_t)(kf * nc16 + c)) * 64 + lane) * 8);
}

// =============================== weight prep ===============================
// Permutes each weight matrix into fragment-major layout (values unchanged).
struct RC { int row, col; };
__device__ __forceinline__ RC unperm(int tl, int lg_nc16) {
  int frag = tl >> 9, ln = (tl >> 3) & 63, j = tl & 7;
  int kf = frag >> lg_nc16, c = frag & ((1 << lg_nc16) - 1);
  RC rc; rc.row = c * 16 + (ln & 15); rc.col = kf * 32 + ((ln >> 4) << 3) + j;
  return rc;
}

__global__ void prep_kernel(
    const float* __restrict__ ew0, const float* __restrict__ ew1, const float* __restrict__ ew2,
    const float* __restrict__ dw0, const float* __restrict__ dw1, const float* __restrict__ dw2,
    const float* __restrict__ cw0, const float* __restrict__ cw1, const float* __restrict__ cw2,
    const float* __restrict__ cw3, const float* __restrict__ cw4, const float* __restrict__ cw5,
    const float* __restrict__ xw0, const float* __restrict__ xw1, const float* __restrict__ xw2,
    const float* __restrict__ xw3, const float* __restrict__ xw4, const float* __restrict__ xw5,
    __bf16* __restrict__ wb)
{
  for (int i = blockIdx.x * blockDim.x + threadIdx.x; i < W_TOTAL; i += gridDim.x * blockDim.x) {
    float v;
    if (i < ENC_W1_OFF) {                 // 128x256 per e
      int t = i; int e = t >> 15; RC rc = unperm(t & 32767, 3);
      v = ew0[e * 32768 + rc.row * 256 + rc.col];
    } else if (i < ENC_W2_OFF) {          // 64x128 per e
      int t = i - ENC_W1_OFF; int e = t >> 13; RC rc = unperm(t & 8191, 2);
      v = ew1[e * 8192 + rc.row * 128 + rc.col];
    } else if (i < DEC_W0_OFF) {          // 32x64 per e
      int t = i - ENC_W2_OFF; int e = t >> 11; RC rc = unperm(t & 2047, 1);
      v = ew2[e * 2048 + rc.row * 64 + rc.col];
    } else if (i < DEC_W1_OFF) {          // 64x32 per e
      int t = i - DEC_W0_OFF; int e = t >> 11; RC rc = unperm(t & 2047, 2);
      v = dw0[e * 2048 + rc.row * 32 + rc.col];
    } else if (i < DEC_W2_OFF) {          // 128x64 per e
      int t = i - DEC_W1_OFF; int e = t >> 13; RC rc = unperm(t & 8191, 3);
      v = dw1[e * 8192 + rc.row * 64 + rc.col];
    } else if (i < COMP_W0_OFF) {         // 256x128 per e
      int t = i - DEC_W2_OFF; int e = t >> 15; RC rc = unperm(t & 32767, 4);
      v = dw2[e * 32768 + rc.row * 128 + rc.col];
    } else if (i < COMP_W1_OFF) {         // 256x512 folded
      RC rc = unperm(i - COMP_W0_OFF, 4);
      v = cw0[rc.row * 1024 + rc.col] + cw0[rc.row * 1024 + 512 + rc.col];
    } else if (i < COMP_W2_OFF) {         // 128x768
      RC rc = unperm(i - COMP_W1_OFF, 3); v = cw1[rc.row * 768 + rc.col];
    } else if (i < COMP_W3_OFF) {         // 64x640
      RC rc = unperm(i - COMP_W2_OFF, 2); v = cw2[rc.row * 640 + rc.col];
    } else if (i < COMP_W4_OFF) {         // 32x576
      RC rc = unperm(i - COMP_W3_OFF, 1); v = cw3[rc.row * 576 + rc.col];
    } else if (i < COMP_W5_OFF) {         // 16x544
      RC rc = unperm(i - COMP_W4_OFF, 0); v = cw4[rc.row * 544 + rc.col];
    } else if (i < DCMP_W0_OFF) {         // 32x544, cols >=528 zero-pad
      RC rc = unperm(i - COMP_W5_OFF, 1);
      v = (rc.col < 528) ? cw5[rc.row * 528 + rc.col] : 0.0f;
    } else if (i < DCMP_W1_OFF) {         // 256x32 folded
      RC rc = unperm(i - DCMP_W0_OFF, 4);
      v = xw0[rc.row * 64 + rc.col] + xw0[rc.row * 64 + 32 + rc.col];
    } else if (i < DCMP_W2_OFF) {         // 128x288
      RC rc = unperm(i - DCMP_W1_OFF, 3); v = xw1[rc.row * 288 + rc.col];
    } else if (i < DCMP_W3_OFF) {         // 64x160
      RC rc = unperm(i - DCMP_W2_OFF, 2); v = xw2[rc.row * 160 + rc.col];
    } else if (i < DCMP_W4_OFF) {         // 32x96
      RC rc = unperm(i - DCMP_W3_OFF, 1); v = xw3[rc.row * 96 + rc.col];
    } else if (i < DCMP_W5_OFF) {         // 16x64
      RC rc = unperm(i - DCMP_W4_OFF, 0); v = xw4[rc.row * 64 + rc.col];
    } else {                              // 512x64, cols >=48 zero-pad
      RC rc = unperm(i - DCMP_W5_OFF, 5);
      v = (rc.col < 48) ? xw5[rc.row * 48 + rc.col] : 0.0f;
    }
    wb[i] = (__bf16)v;
  }
}

// =============================== encoder ===================================
// R13 structure (e-major grid, 3 blocks/CU); B-loads now fragment-major.
__global__ __launch_bounds__(256, 3)
void enc_kernel(const float* __restrict__ x, const __bf16* __restrict__ wb,
                const float* __restrict__ b0, const float* __restrict__ b1,
                const float* __restrict__ b2, __bf16* __restrict__ zout)
{
  __shared__ __align__(16) char smem[51200];
  __bf16* xs = (__bf16*)smem;            // [64][264], dead after L0
  __bf16* h1 = (__bf16*)(smem + 33792);  // [64][136]
  __bf16* h2 = (__bf16*)smem;            // [64][72], aliases xs
  const int e = blockIdx.x;              // e-major dispatch
  const int m0 = blockIdx.y * 64;
  const int tid = threadIdx.x;
  const int lane = tid & 63, wv = tid >> 6;
  const int l15 = lane & 15, hi8 = (lane >> 4) * 8, rloc = (lane >> 4) * 4;

  const float* xblk = x + (size_t)m0 * 4096 + e * 256;
  #pragma unroll
  for (int i = 0; i < 16; ++i) {
    int idx = tid + i * 256;
    int r = idx >> 6, c4 = (idx & 63) * 4;
    float4 v = *(const float4*)(xblk + (size_t)r * 4096 + c4);
    bf16x4 o = { (__bf16)v.x, (__bf16)v.y, (__bf16)v.z, (__bf16)v.w };
    *(bf16x4*)&xs[r * 264 + c4] = o;
  }
  __syncthreads();

  // L0: N=128, K=256. wave covers cols [wv*32, wv*32+32)
  {
    const __bf16* W = wb + ENC_W0_OFF + e * 32768;
    f32x4 acc[4][2];
    #pragma unroll
    for (int cf = 0; cf < 2; ++cf) {
      float bv = b0[e * 128 + wv * 32 + cf * 16 + l15];
      f32x4 bvv = {bv, bv, bv, bv};
      #pragma unroll
      for (int rf = 0; rf < 4; ++rf) acc[rf][cf] = bvv;
    }
    #pragma unroll
    for (int ks = 0; ks < 8; ++ks) {
      bf16x8 a[4], bb[2];
      #pragma unroll
      for (int rf = 0; rf < 4; ++rf) a[rf] = *(const bf16x8*)&xs[(rf * 16 + l15) * 264 + ks * 32 + hi8];
      #pragma unroll
      for (int cf = 0; cf < 2; ++cf) bb[cf] = ldB(W, 8, ks, wv * 2 + cf, lane);
      #pragma unroll
      for (int rf = 0; rf < 4; ++rf)
        #pragma unroll
        for (int cf = 0; cf < 2; ++cf)
          acc[rf][cf] = MFMA16(a[rf], bb[cf], acc[rf][cf]);
    }
    #pragma unroll
    for (int rf = 0; rf < 4; ++rf)
      #pragma unroll
      for (int cf = 0; cf < 2; ++cf)
        #pragma unroll
        for (int r = 0; r < 4; ++r)
          h1[(rf * 16 + rloc + r) * 136 + wv * 32 + cf * 16 + l15] = (__bf16)sigm(acc[rf][cf][r]);
  }
  __syncthreads();

  // L1: N=64, K=128. h2 overwrites the xs alias region (xs fully dead).
  {
    const __bf16* W = wb + ENC_W1_OFF + e * 8192;
    f32x4 acc[4];
    float bv = b1[e * 64 + wv * 16 + l15];
    f32x4 bvv = {bv, bv, bv, bv};
    #pragma unroll
    for (int rf = 0; rf < 4; ++rf) acc[rf] = bvv;
    #pragma unroll
    for (int ks = 0; ks < 4; ++ks) {
      bf16x8 a[4];
      #pragma unroll
      for (int rf = 0; rf < 4; ++rf) a[rf] = *(const bf16x8*)&h1[(rf * 16 + l15) * 136 + ks * 32 + hi8];
      bf16x8 bb = ldB(W, 4, ks, wv, lane);
      #pragma unroll
      for (int rf = 0; rf < 4; ++rf) acc[rf] = MFMA16(a[rf], bb, acc[rf]);
    }
    #pragma unroll
    for (int rf = 0; rf < 4; ++rf)
      #pragma unroll
      for (int r = 0; r < 4; ++r)
        h2[(rf * 16 + rloc + r) * 72 + wv * 16 + l15] = (__bf16)sigm(acc[rf][r]);
  }
  __syncthreads();

  // L2: N=32, K=64, no sigmoid. waves 0,1 only.
  if (wv < 2) {
    const __bf16* W = wb + ENC_W2_OFF + e * 2048;
    f32x4 acc[4];
    float bv = b2[e * 32 + wv * 16 + l15];
    f32x4 bvv = {bv, bv, bv, bv};
    #pragma unroll
    for (int rf = 0; rf < 4; ++rf) acc[rf] = bvv;
    #pragma unroll
    for (int ks = 0; ks < 2; ++ks) {
      bf16x8 a[4];
      #pragma unroll
      for (int rf = 0; rf < 4; ++rf) a[rf] = *(const bf16x8*)&h2[(rf * 16 + l15) * 72 + ks * 32 + hi8];
      bf16x8 bb = ldB(W, 2, ks, wv, lane);
      #pragma unroll
      for (int rf = 0; rf < 4; ++rf) acc[rf] = MFMA16(a[rf], bb, acc[rf]);
    }
    #pragma unroll
    for (int rf = 0; rf < 4; ++rf)
      #pragma unroll
      for (int r = 0; r < 4; ++r)
        zout[(size_t)(m0 + rf * 16 + rloc + r) * 512 + e * 32 + wv * 16 + l15] = (__bf16)acc[rf][r];
  }
}

// ==================== 8-wave residual layer, 64-row tile ===================
template<int NF, int KT, int ZKS, int ZLD, int SKS, int SLD, int DLD, bool SIG>
__device__ __forceinline__ void rlayer(const __bf16* __restrict__ W, const float* __restrict__ bias,
                                       const __bf16* __restrict__ zp, const __bf16* __restrict__ sp,
                                       __bf16* __restrict__ dst,
                                       int wv, int lane, int l15, int hi8, int rloc)
{
  constexpr int NJ = (NF >= 32) ? 4 : ((NF >= 16) ? 2 : 1);
  constexpr int NR = (NF >= 8) ? 4 : ((NF == 4) ? 2 : 1);
  int c0, row0;
  if constexpr (NF >= 8)       { c0 = wv;      row0 = 0; }
  else if constexpr (NF == 4)  { c0 = wv & 3;  row0 = (wv >> 2) * 32; }
  else if constexpr (NF == 2)  { c0 = wv & 1;  row0 = (wv >> 1) * 16; }
  else                         { if (wv >= 4) return; c0 = 0; row0 = wv * 16; }
  f32x4 acc[NR][NJ];
  #pragma unroll
  for (int j = 0; j < NJ; ++j) {
    float bv = bias[(c0 + 8 * j) * 16 + l15];
    f32x4 b4 = {bv, bv, bv, bv};
    #pragma unroll
    for (int rf = 0; rf < NR; ++rf) acc[rf][j] = b4;
  }
  #pragma unroll
  for (int ks = 0; ks < ZKS; ++ks) {
    bf16x8 a[NR];
    #pragma unroll
    for (int rf = 0; rf < NR; ++rf)
      a[rf] = *(const bf16x8*)&zp[(size_t)(row0 + rf * 16 + l15) * ZLD + ks * 32 + hi8];
    #pragma unroll
    for (int j = 0; j < NJ; ++j) {
      bf16x8 b = ldB(W, NF, ks, c0 + 8 * j, lane);
      #pragma unroll
      for (int rf = 0; rf < NR; ++rf) acc[rf][j] = MFMA16(a[rf], b, acc[rf][j]);
    }
  }
  if constexpr (SKS > 0) {
    #pragma unroll
    for (int ks = 0; ks < SKS; ++ks) {
      bf16x8 a[NR];
      #pragma unroll
      for (int rf = 0; rf < NR; ++rf)
        a[rf] = *(const bf16x8*)&sp[(size_t)(row0 + rf * 16 + l15) * SLD + ks * 32 + hi8];
      #pragma unroll
      for (int j = 0; j < NJ; ++j) {
        bf16x8 b = ldB(W, NF, ZKS + ks, c0 + 8 * j, lane);
        #pragma unroll
        for (int rf = 0; rf < NR; ++rf) acc[rf][j] = MFMA16(a[rf], b, acc[rf][j]);
      }
    }
  }
  #pragma unroll
  for (int j = 0; j < NJ; ++j)
    #pragma unroll
    for (int rf = 0; rf < NR; ++rf)
      #pragma unroll
      for (int r = 0; r < 4; ++r) {
        float v = acc[rf][j][r];
        dst[(size_t)(row0 + rf * 16 + rloc + r) * DLD + (c0 + 8 * j) * 16 + l15] =
            (__bf16)(SIG ? sigm(v) : v);
      }
}

// ===================== middle: comp + decomp fused =========================
struct MidBias {
  const float *c0, *c1, *c2, *c3, *c4, *c5;
  const float *x0, *x1, *x2, *x3, *x4, *x5;
};

__global__ __launch_bounds__(512, 2)
void mid_kernel(const __bf16* __restrict__ zin, const __bf16* __restrict__ wb,
                MidBias mb, __bf16* __restrict__ zhout)
{
  __shared__ __bf16 zs[64 * 520];
  __shared__ __bf16 sA[64 * 264];
  __shared__ __bf16 sB[64 * 136];
  __shared__ __bf16 zsm[64 * 40];
  const int tid = threadIdx.x;
  const int wv = tid >> 6, lane = tid & 63;
  const int l15 = lane & 15, hi8 = (lane >> 4) * 8, rloc = (lane >> 4) * 4;
  const int m0 = blockIdx.x * 64;

  #pragma unroll
  for (int i = 0; i < 8; ++i) {
    int idx = tid + i * 512;
    int r = idx >> 6, c8 = (idx & 63) * 8;
    *(bf16x8*)&zs[r * 520 + c8] = *(const bf16x8*)(zin + (size_t)(m0 + r) * 512 + c8);
  }
  __syncthreads();
  // ---- compressor ----
  rlayer<16, 512, 16, 520, 0,   0, 264, true >(wb + COMP_W0_OFF, mb.c0, zs, nullptr, sA, wv, lane, l15, hi8, rloc); __syncthreads();
  rlayer< 8, 768, 16, 520, 8, 264, 136, true >(wb + COMP_W1_OFF, mb.c1, zs, sA, sB, wv, lane, l15, hi8, rloc); __syncthreads();
  rlayer< 4, 640, 16, 520, 4, 136, 264, true >(wb + COMP_W2_OFF, mb.c2, zs, sB, sA, wv, lane, l15, hi8, rloc); __syncthreads();
  rlayer< 2, 576, 16, 520, 2, 264, 136, true >(wb + COMP_W3_OFF, mb.c3, zs, sA, sB, wv, lane, l15, hi8, rloc); __syncthreads();
  rlayer< 1, 544, 16, 520, 1, 136, 264, true >(wb + COMP_W4_OFF, mb.c4, zs, sB, sA, wv, lane, l15, hi8, rloc);
  for (int i = tid; i < 64 * 16; i += 512) sA[(i >> 4) * 264 + 16 + (i & 15)] = (__bf16)0.0f;
  __syncthreads();
  rlayer< 2, 544, 16, 520, 1, 264, 40, false>(wb + COMP_W5_OFF, mb.c5, zs, sA, zsm, wv, lane, l15, hi8, rloc);
  __syncthreads();
  // ---- decompressor ----
  rlayer<16,  32, 1, 40, 0,   0, 264, true >(wb + DCMP_W0_OFF, mb.x0, zsm, nullptr, sA, wv, lane, l15, hi8, rloc); __syncthreads();
  rlayer< 8, 288, 1, 40, 8, 264, 136, true >(wb + DCMP_W1_OFF, mb.x1, zsm, sA, sB, wv, lane, l15, hi8, rloc); __syncthreads();
  rlayer< 4, 160, 1, 40, 4, 136, 264, true >(wb + DCMP_W2_OFF, mb.x2, zsm, sB, sA, wv, lane, l15, hi8, rloc); __syncthreads();
  rlayer< 2,  96, 1, 40, 2, 264, 136, true >(wb + DCMP_W3_OFF, mb.x3, zsm, sA, sB, wv, lane, l15, hi8, rloc); __syncthreads();
  rlayer< 1,  64, 1, 40, 1, 136, 264, true >(wb + DCMP_W4_OFF, mb.x4, zsm, sB, sA, wv, lane, l15, hi8, rloc);
  for (int i = tid; i < 64 * 16; i += 512) sA[(i >> 4) * 264 + 16 + (i & 15)] = (__bf16)0.0f;
  __syncthreads();
  rlayer<32,  64, 1, 40, 1, 264, 512, false>(wb + DCMP_W5_OFF, mb.x5, zsm, sA,
                                             zhout + (size_t)m0 * 512, wv, lane, l15, hi8, rloc);
}

// =============================== decoder ===================================
// R13 structure (e-major grid, 4 blocks/CU); B-loads fragment-major.
__global__ __launch_bounds__(256, 4)
void dec_kernel(const __bf16* __restrict__ zin, const __bf16* __restrict__ wb,
                const float* __restrict__ b0, const float* __restrict__ b1,
                const float* __restrict__ b2, float* __restrict__ out)
{
  __shared__ __bf16 zs[64][40];
  __shared__ __bf16 h1[64][72];
  __shared__ __bf16 h2[64][136];
  const int e = blockIdx.x;              // e-major dispatch
  const int m0 = blockIdx.y * 64;
  const int tid = threadIdx.x;
  const int lane = tid & 63, wv = tid >> 6;
  const int l15 = lane & 15, hi8 = (lane >> 4) * 8, rloc = (lane >> 4) * 4;

  {
    int r = tid >> 2, c = (tid & 3) * 8;
    *(bf16x8*)&zs[r][c] = *(const bf16x8*)(zin + (size_t)(m0 + r) * 512 + e * 32 + c);
  }
  __syncthreads();

  // L0: N=64, K=32
  {
    const __bf16* W = wb + DEC_W0_OFF + e * 2048;
    f32x4 acc[4];
    float bv = b0[e * 64 + wv * 16 + l15];
    f32x4 bvv = {bv, bv, bv, bv};
    #pragma unroll
    for (int rf = 0; rf < 4; ++rf) acc[rf] = bvv;
    bf16x8 a[4];
    #pragma unroll
    for (int rf = 0; rf < 4; ++rf) a[rf] = *(const bf16x8*)&zs[rf * 16 + l15][hi8];
    bf16x8 bb = ldB(W, 4, 0, wv, lane);
    #pragma unroll
    for (int rf = 0; rf < 4; ++rf) acc[rf] = MFMA16(a[rf], bb, acc[rf]);
    #pragma unroll
    for (int rf = 0; rf < 4; ++rf)
      #pragma unroll
      for (int r = 0; r < 4; ++r)
        h1[rf * 16 + rloc + r][wv * 16 + l15] = (__bf16)sigm(acc[rf][r]);
  }
  __syncthreads();

  // L1: N=128, K=64
  {
    const __bf16* W = wb + DEC_W1_OFF + e * 8192;
    f32x4 acc[4][2];
    #pragma unroll
    for (int cf = 0; cf < 2; ++cf) {
      float bv = b1[e * 128 + wv * 32 + cf * 16 + l15];
      f32x4 bvv = {bv, bv, bv, bv};
      #pragma unroll
      for (int rf = 0; rf < 4; ++rf) acc[rf][cf] = bvv;
    }
    #pragma unroll
    for (int ks = 0; ks < 2; ++ks) {
      bf16x8 a[4], bb[2];
      #pragma unroll
      for (int rf = 0; rf < 4; ++rf) a[rf] = *(const bf16x8*)&h1[rf * 16 + l15][ks * 32 + hi8];
      #pragma unroll
      for (int cf = 0; cf < 2; ++cf) bb[cf] = ldB(W, 8, ks, wv * 2 + cf, lane);
      #pragma unroll
      for (int rf = 0; rf < 4; ++rf)
        #pragma unroll
        for (int cf = 0; cf < 2; ++cf)
          acc[rf][cf] = MFMA16(a[rf], bb[cf], acc[rf][cf]);
    }
    #pragma unroll
    for (int rf = 0; rf < 4; ++rf)
      #pragma unroll
      for (int cf = 0; cf < 2; ++cf)
        #pragma unroll
        for (int r = 0; r < 4; ++r)
          h2[rf * 16 + rloc + r][wv * 32 + cf * 16 + l15] = (__bf16)sigm(acc[rf][cf][r]);
  }
  __syncthreads();

  // L2: N=256, K=128, no sigmoid, fp32 out
  {
    const __bf16* W = wb + DEC_W2_OFF + e * 32768;
    f32x4 acc[4][4];
    #pragma unroll
    for (int cf = 0; cf < 4; ++cf) {
      float bv = b2[e * 256 + wv * 64 + cf * 16 + l15];
      f32x4 bvv = {bv, bv, bv, bv};
      #pragma unroll
      for (int rf = 0; rf < 4; ++rf) acc[rf][cf] = bvv;
    }
    #pragma unroll
    for (int ks = 0; ks < 4; ++ks) {
      bf16x8 a[4], bb[4];
      #pragma unroll
      for (int rf = 0; rf < 4; ++rf) a[rf] = *(const bf16x8*)&h2[rf * 16 + l15][ks * 32 + hi8];
      #pragma unroll
      for (int cf = 0; cf < 4; ++cf) bb[cf] = ldB(W, 16, ks, wv * 4 + cf, lane);
      #pragma unroll
      for (int rf = 0; rf < 4; ++rf)
        #pragma unroll
        for (int cf = 0; cf < 4; ++cf)
          acc[rf][cf] = MFMA16(a[rf], bb[cf], acc[rf][cf]);
    }
    #pragma unroll
    for (int rf = 0; rf < 4; ++rf)
      #pragma unroll
      for (int cf = 0; cf < 4; ++cf)
        #pragma unroll
        for (int r = 0; r < 4; ++r)
          out[(size_t)(m0 + rf * 16 + rloc + r) * 4096 + e * 256 + wv * 64 + cf * 16 + l15] =
              acc[rf][cf][r];
  }
}

// =============================== launcher ==================================
extern "C" void kernel_launch(void* const* d_in, const int* in_sizes, int n_in,
                              void* d_out, int out_size, void* d_ws, size_t ws_size,
                              hipStream_t stream) {
  (void)in_sizes; (void)n_in; (void)out_size; (void)ws_size;
  const float* x   = (const float*)d_in[0];
  const float* ew0 = (const float*)d_in[1];  const float* eb0 = (const float*)d_in[2];
  const float* ew1 = (const float*)d_in[3];  const float* eb1 = (const float*)d_in[4];
  const float* ew2 = (const float*)d_in[5];  const float* eb2 = (const float*)d_in[6];
  const float* dw0 = (const float*)d_in[7];  const float* db0 = (const float*)d_in[8];
  const float* dw1 = (const float*)d_in[9];  const float* db1 = (const float*)d_in[10];
  const float* dw2 = (const float*)d_in[11]; const float* db2 = (const float*)d_in[12];
  const float* cw[6]; const float* cb[6];
  for (int i = 0; i < 6; ++i) { cw[i] = (const float*)d_in[13 + 2 * i]; cb[i] = (const float*)d_in[14 + 2 * i]; }
  const float* xw[6]; const float* xb[6];
  for (int i = 0; i < 6; ++i) { xw[i] = (const float*)d_in[25 + 2 * i]; xb[i] = (const float*)d_in[26 + 2 * i]; }

  __bf16* wbuf   = (__bf16*)d_ws;
  __bf16* zstack = (__bf16*)((char*)d_ws + ZS_BYTES_OFF);  // z_stack, then z_stack_hat in-place
  float* out = (float*)d_out;

  prep_kernel<<<1024, 256, 0, stream>>>(ew0, ew1, ew2, dw0, dw1, dw2,
                                        cw[0], cw[1], cw[2], cw[3], cw[4], cw[5],
                                        xw[0], xw[1], xw[2], xw[3], xw[4], xw[5], wbuf);
  enc_kernel<<<dim3(16, 512), 256, 0, stream>>>(x, wbuf, eb0, eb1, eb2, zstack);
  MidBias mb = {cb[0], cb[1], cb[2], cb[3], cb[4], cb[5],
                xb[0], xb[1], xb[2], xb[3], xb[4], xb[5]};
  mid_kernel<<<512, 512, 0, stream>>>(zstack, wbuf, mb, zstack);
  dec_kernel<<<dim3(16, 512), 256, 0, stream>>>(zstack, wbuf, db0, db1, db2, out);
}